// Round 10
// baseline (560.233 us; speedup 1.0000x reference)
//
#include <hip/hip_runtime.h>
#include <stdint.h>

#define S_LEN  1024
#define BATCH  8
#define DMODEL 768
#define NHEAD  12
#define HDIM   64
#define NEXP   8
#define FFDIM  3072
#define NTOK   8192     // S*B
#define D3     2304     // 3*D
#define NGATH  16384    // NTOK * topk(2)
#define MAXWL  80       // max live 256-row tiles across experts (64+7, padded)

typedef unsigned short u16;
typedef unsigned int   u32;
typedef __attribute__((ext_vector_type(8))) short bf16x8;
typedef __attribute__((ext_vector_type(4))) float f32x4;
typedef __attribute__((ext_vector_type(4))) short s16x4;

__device__ __forceinline__ u16 f2bf(float f){
  u32 x = __float_as_uint(f);
  x += 0x7fffu + ((x >> 16) & 1u);          // RNE
  return (u16)(x >> 16);
}
__device__ __forceinline__ float bf2f(u16 u){
  return __uint_as_float(((u32)u) << 16);
}
__device__ __forceinline__ u32 pkbf(float a, float b){   // lo=bf(a), hi=bf(b)
  u32 d; asm("v_cvt_pk_bf16_f32 %0, %1, %2" : "=v"(d) : "v"(a), "v"(b)); return d;
}
__device__ __forceinline__ void gl_lds16(const void* g, void* l){
  __builtin_amdgcn_global_load_lds(
      (const __attribute__((address_space(1))) u32*)(uintptr_t)g,
      (__attribute__((address_space(3))) u32*)(u32)(uintptr_t)l,
      16, 0, 0);
}
// XOR swizzle for 128B-stride row-major bf16 LDS tiles (G4 fix), 16B-chunk preserving
__device__ __forceinline__ int swz64(int r){ return ((r & 7) ^ ((r >> 3) & 7)) << 4; }

// ---------------- elementwise fp32 -> bf16 convert ----------------
__global__ __launch_bounds__(256)
void cvt_bf16(const float* __restrict__ in, u16* __restrict__ out, int n)
{
  int i = (blockIdx.x * 256 + threadIdx.x) * 4;
  if (i + 3 < n) {
    float4 v = *(const float4*)(in + i);
    out[i]     = f2bf(v.x);
    out[i + 1] = f2bf(v.y);
    out[i + 2] = f2bf(v.z);
    out[i + 3] = f2bf(v.w);
  }
}

// --------------- transpose + convert: in[rows][cols] f32 -> out[cols][rows] bf16 ---------------
__global__ __launch_bounds__(256)
void transpose_cvt(const float* __restrict__ in, u16* __restrict__ out, int rows, int cols)
{
  __shared__ float tile[32][33];
  const size_t eo = (size_t)blockIdx.z * rows * cols;
  in  += eo; out += eo;
  const int bx = blockIdx.x * 32, by = blockIdx.y * 32;
  const int tx = threadIdx.x, ty = threadIdx.y;   // (32, 8)
  #pragma unroll
  for (int i = 0; i < 4; i++)
    tile[ty + i * 8][tx] = in[(size_t)(by + ty + i * 8) * cols + bx + tx];
  __syncthreads();
  #pragma unroll
  for (int i = 0; i < 4; i++)
    out[(size_t)(bx + ty + i * 8) * rows + by + tx] = f2bf(tile[tx][ty + i * 8]);
}

// ---------------- LayerNorm (row = 768) -> bf16 ----------------
__global__ __launch_bounds__(256)
void ln_fwd(const float* __restrict__ x, const float* __restrict__ w, const float* __restrict__ b,
            u16* __restrict__ out)
{
  const int t = blockIdx.x, tid = threadIdx.x;
  const float* xr = x + (size_t)t * DMODEL;
  const float v0 = xr[tid], v1 = xr[tid + 256], v2 = xr[tid + 512];
  float s = v0 + v1 + v2, ss = v0 * v0 + v1 * v1 + v2 * v2;
  #pragma unroll
  for (int d = 1; d < 64; d <<= 1) { s += __shfl_xor(s, d); ss += __shfl_xor(ss, d); }
  __shared__ float rs[4], rq[4];
  if ((tid & 63) == 0) { rs[tid >> 6] = s; rq[tid >> 6] = ss; }
  __syncthreads();
  s  = rs[0] + rs[1] + rs[2] + rs[3];
  ss = rq[0] + rq[1] + rq[2] + rq[3];
  const float mean = s * (1.f / DMODEL);
  const float rstd = rsqrtf(ss * (1.f / DMODEL) - mean * mean + 1e-5f);
  u16* orow = out + (size_t)t * DMODEL;
  orow[tid]       = f2bf((v0 - mean) * rstd * w[tid]       + b[tid]);
  orow[tid + 256] = f2bf((v1 - mean) * rstd * w[tid + 256] + b[tid + 256]);
  orow[tid + 512] = f2bf((v2 - mean) * rstd * w[tid + 512] + b[tid + 512]);
}

// ---------------- LN2 + gate logits + top-2 routing ----------------
__global__ __launch_bounds__(256)
void ln2_gate(const float* __restrict__ x1, const float* __restrict__ w, const float* __restrict__ b,
              const float* __restrict__ gate_w, u16* __restrict__ h2,
              float* __restrict__ logits, float* __restrict__ selw, int* __restrict__ seli)
{
  const int t = blockIdx.x, tid = threadIdx.x;
  const float* xr = x1 + (size_t)t * DMODEL;
  const float v0 = xr[tid], v1 = xr[tid + 256], v2 = xr[tid + 512];
  float s = v0 + v1 + v2, ss = v0 * v0 + v1 * v1 + v2 * v2;
  #pragma unroll
  for (int d = 1; d < 64; d <<= 1) { s += __shfl_xor(s, d); ss += __shfl_xor(ss, d); }
  __shared__ float rs[4], rq[4];
  if ((tid & 63) == 0) { rs[tid >> 6] = s; rq[tid >> 6] = ss; }
  __syncthreads();
  s  = rs[0] + rs[1] + rs[2] + rs[3];
  ss = rq[0] + rq[1] + rq[2] + rq[3];
  const float mean = s * (1.f / DMODEL);
  const float rstd = rsqrtf(ss * (1.f / DMODEL) - mean * mean + 1e-5f);
  __shared__ float row[DMODEL];
  const float y0 = (v0 - mean) * rstd * w[tid]       + b[tid];
  const float y1 = (v1 - mean) * rstd * w[tid + 256] + b[tid + 256];
  const float y2 = (v2 - mean) * rstd * w[tid + 512] + b[tid + 512];
  row[tid] = y0; row[tid + 256] = y1; row[tid + 512] = y2;
  u16* hr = h2 + (size_t)t * DMODEL;
  hr[tid] = f2bf(y0); hr[tid + 256] = f2bf(y1); hr[tid + 512] = f2bf(y2);
  __syncthreads();
  __shared__ float lg[NEXP];
  if (tid < 64) {
    const int e = tid >> 3, j = tid & 7;
    const float* gw = gate_w + e * DMODEL;
    float a = 0.f;
    for (int d = j; d < DMODEL; d += 8) a += row[d] * gw[d];
    a += __shfl_xor(a, 1); a += __shfl_xor(a, 2); a += __shfl_xor(a, 4);
    if (j == 0) lg[e] = a;
  }
  __syncthreads();
  if (tid < NEXP) logits[(size_t)t * NEXP + tid] = lg[tid];
  if (tid == 0) {
    int ia = 0, ib = -1;
    float va = -1e30f, vb = -1e30f;
    #pragma unroll
    for (int e = 0; e < NEXP; e++) {
      const float p = lg[e];
      if (p > va)      { vb = va; ib = ia; va = p; ia = e; }
      else if (p > vb) { vb = p; ib = e; }
    }
    const float pb = __expf(vb - va);          // softmax of {va,vb}; full-Z cancels in renorm
    const float inv = 1.f / (1.f + pb);
    selw[2 * t]     = inv;
    selw[2 * t + 1] = pb * inv;
    seli[2 * t]     = ia;
    seli[2 * t + 1] = ib;
  }
}

// ---------------- deterministic token->expert compaction ----------------
__global__ __launch_bounds__(256)
void route_count(const int* __restrict__ seli, int* __restrict__ blkcnt)
{
  __shared__ int c[NEXP];
  const int tid = threadIdx.x;
  if (tid < NEXP) c[tid] = 0;
  __syncthreads();
  const int t = blockIdx.x * 256 + tid;
  atomicAdd(&c[seli[2 * t]], 1);
  atomicAdd(&c[seli[2 * t + 1]], 1);
  __syncthreads();
  if (tid < NEXP) blkcnt[blockIdx.x * NEXP + tid] = c[tid];
}

// also builds the live-tile work list (256-row tiles): wl[i] = (e<<16)|bm_local, nwork[0] = count
__global__ void route_scan(const int* __restrict__ blkcnt, int* __restrict__ offs,
                           int* __restrict__ blkbase, int* __restrict__ wl, int* __restrict__ nwork)
{
  const int tid = threadIdx.x;   // 64 threads
  __shared__ int tot[NEXP];
  __shared__ int off_s[NEXP + 1];
  if (tid < NEXP) {
    int s = 0;
    for (int blk = 0; blk < 32; blk++) s += blkcnt[blk * NEXP + tid];
    tot[tid] = s;
  }
  __syncthreads();
  if (tid == 0) {
    int run = 0;
    for (int e = 0; e < NEXP; e++) { off_s[e] = run; run += tot[e]; }
    off_s[NEXP] = run;
    int nw = 0;
    for (int e = 0; e < NEXP; e++) {
      const int nb = (tot[e] + 255) >> 8;
      for (int i2 = 0; i2 < nb; i2++) wl[nw++] = (e << 16) | i2;
    }
    nwork[0] = nw;
  }
  __syncthreads();
  if (tid <= NEXP) offs[tid] = off_s[tid];
  if (tid < NEXP) {
    int run = off_s[tid];
    for (int blk = 0; blk < 32; blk++) { blkbase[blk * NEXP + tid] = run; run += blkcnt[blk * NEXP + tid]; }
  }
}

__global__ __launch_bounds__(256)
void route_place(const int* __restrict__ seli, const int* __restrict__ blkbase,
                 int* __restrict__ perm, int* __restrict__ posmap)
{
  __shared__ int cnts[2][4][NEXP];
  __shared__ int base[NEXP];
  const int tid = threadIdx.x, l = tid & 63, w = tid >> 6, blk = blockIdx.x;
  const int t = blk * 256 + tid;
  const unsigned long long ltm = (1ull << l) - 1ull;
  int my_e[2], my_r[2];
  my_e[0] = seli[2 * t]; my_e[1] = seli[2 * t + 1];
  my_r[0] = 0; my_r[1] = 0;
  if (tid < NEXP) base[tid] = blkbase[blk * NEXP + tid];
  #pragma unroll
  for (int k = 0; k < 2; k++) {
    #pragma unroll
    for (int ee = 0; ee < NEXP; ee++) {
      const unsigned long long msk = __ballot(my_e[k] == ee);
      if (my_e[k] == ee) my_r[k] = (int)__popcll(msk & ltm);
      if (l == ee) cnts[k][w][ee] = (int)__popcll(msk);
    }
  }
  __syncthreads();
  #pragma unroll
  for (int k = 0; k < 2; k++) {
    const int e = my_e[k];
    int pre = base[e];
    for (int k2 = 0; k2 < 2; k2++)
      for (int w2 = 0; w2 < 4; w2++)
        if (k2 < k || (k2 == k && w2 < w)) pre += cnts[k2][w2][e];
    const int pos = pre + my_r[k];
    perm[pos] = t;
    posmap[2 * t + k] = pos;
  }
}

// ------- 256x256x64 bf16 MFMA GEMM: 8 waves, 4-phase/K-tile interleave (T2+T3+T4+T5) -------
// Per phase: {ds_read subtile (8 or 4 b128; bv read on ks-entry, reused next phase) ||
// stage 1 A-chunk + 1 B-chunk of NEXT K-tile into other buffer -> s_barrier -> lgkmcnt(0)
// -> setprio(1) 16 MFMA setprio(0) -> s_barrier}. Counted vmcnt(2) at P0 (issue chunk0
// first, retire prev tile's 8, keep 2 in flight - T4 never drains to 0 mid-loop).
// Race-free: stages only touch buf[cur^1]; overwrites of buf[cur] issue after P3 barrier.
template<int MODE>  // 0=QKV(bf16,+bias) 2=FFN1(gelu,bf16) 3=FFN2(bf16)
__global__ __launch_bounds__(512, 2)
void gemm256(const u16* __restrict__ A, const u16* __restrict__ Bw,
             int M, int N, int Kd,
             const float* __restrict__ bias,
             void* __restrict__ outp,
             const int* __restrict__ perm, const int* __restrict__ offs,
             const int* __restrict__ wl, const int* __restrict__ nwork)
{
  extern __shared__ u16 smem[];  // 128 KB: buf0{A16384,B16384} buf1{A,B}
  const int tid = threadIdx.x;
  const int l   = tid & 63;
  const int w   = tid >> 6;                // 8 waves: 2(m) x 4(n)
  const int wm  = w >> 2, wn = w & 3;
  const int bn  = blockIdx.y;

  int gbase = 0, cnt = M, e = 0, bm = blockIdx.x;
  if (MODE >= 2) {
    if (blockIdx.x >= nwork[0]) return;    // compact work list (uniform exit, pre-barrier)
    const int wk = wl[blockIdx.x];
    e  = wk >> 16;
    bm = wk & 0xffff;
    gbase = offs[e];
    cnt   = offs[e + 1] - gbase;
  }
  const u16*   Bp = Bw   + (MODE >= 2 ? (size_t)e * N * Kd : 0);
  const float* bp = bias + (MODE >= 2 ? e * N : 0);

  // staging addresses: chunk i = rows (tid+512i)>>3 of the 256-row tile
  int arow[4], acol[4], brow[4];
  #pragma unroll
  for (int i = 0; i < 4; i++) {
    const int c = tid + 512 * i;
    const int r = c >> 3;
    const int f = (r & 7) ^ ((r >> 3) & 7);
    acol[i] = ((c & 7) ^ f) * 8;           // pre-swizzled source column (16B chunk)
    brow[i] = bn * 256 + r;
    int g;
    if (MODE == 2)      { int gp = gbase + bm * 256 + r; if (gp > NGATH - 1) gp = NGATH - 1; g = perm[gp]; }
    else if (MODE == 3) { int gp = gbase + bm * 256 + r; if (gp > NGATH - 1) gp = NGATH - 1; g = gp; }
    else                g = bm * 256 + r;
    arow[i] = g;
  }

  f32x4 acc[8][4] = {};
  const int nk = Kd >> 6;

  // row byte-offsets for fragment reads (per-lane constants)
  int aoff[8], boff[4];
  #pragma unroll
  for (int m = 0; m < 8; m++) {
    const int row = wm * 128 + m * 16 + (l & 15);
    aoff[m] = (row * 128 + (l >> 4) * 16) ^ swz64(row);
  }
  #pragma unroll
  for (int n = 0; n < 4; n++) {
    const int row = wn * 64 + n * 16 + (l & 15);
    boff[n] = (row * 128 + (l >> 4) * 16) ^ swz64(row);
  }

  // prologue: stage Kt0 into buf0
  #pragma unroll
  for (int i = 0; i < 4; i++) {
    gl_lds16(A  + (size_t)arow[i] * Kd + acol[i], &smem[(tid + 512 * i) * 8]);
    gl_lds16(Bp + (size_t)brow[i] * Kd + acol[i], &smem[16384 + (tid + 512 * i) * 8]);
  }

  int cur = 0;
  for (int kt = 0; kt < nk; kt++) {
    const bool pf = (kt + 1 < nk);
    const int  kb = (kt + 1) * 64;
    u16* nA = smem + (cur ^ 1) * 32768;
    u16* nB = nA + 16384;
    const char* Ac = (const char*)(smem + cur * 32768);
    const char* Bc = (const char*)(smem + cur * 32768 + 16384);
    bf16x8 bv[4], af[4];

    // ---------------- P0: ks0, m0-3 ----------------
    if (pf) {
      gl_lds16(A  + (size_t)arow[0] * Kd + kb + acol[0], &nA[tid * 8]);
      gl_lds16(Bp + (size_t)brow[0] * Kd + kb + acol[0], &nB[tid * 8]);
      asm volatile("s_waitcnt vmcnt(2)" ::: "memory");   // retire Kt(kt)'s 8; keep 2 in flight
    } else {
      asm volatile("s_waitcnt vmcnt(0)" ::: "memory");
    }
    __builtin_amdgcn_s_barrier();                        // buf[cur] fully resident
    __builtin_amdgcn_sched_barrier(0);
    #pragma unroll
    for (int n = 0; n < 4; n++) bv[n] = *(const bf16x8*)(Bc + boff[n]);
    #pragma unroll
    for (int m = 0; m < 4; m++) af[m] = *(const bf16x8*)(Ac + aoff[m]);
    asm volatile("s_waitcnt lgkmcnt(0)" ::: "memory");
    __builtin_amdgcn_sched_barrier(0);
    __builtin_amdgcn_s_setprio(1);
    #pragma unroll
    for (int m = 0; m < 4; m++)
      #pragma unroll
      for (int n = 0; n < 4; n++)
        acc[m][n] = __builtin_amdgcn_mfma_f32_16x16x32_bf16(bv[n], af[m], acc[m][n], 0, 0, 0);
    __builtin_amdgcn_s_setprio(0);
    __builtin_amdgcn_s_barrier();
    __builtin_amdgcn_sched_barrier(0);

    // ---------------- P1: ks0, m4-7 (bv reused) ----------------
    #pragma unroll
    for (int m = 0; m < 4; m++) af[m] = *(const bf16x8*)(Ac + aoff[m + 4]);
    if (pf) {
      gl_lds16(A  + (size_t)arow[1] * Kd + kb + acol[1], &nA[(tid + 512) * 8]);
      gl_lds16(Bp + (size_t)brow[1] * Kd + kb + acol[1], &nB[(tid + 512) * 8]);
    }
    __builtin_amdgcn_s_barrier();
    asm volatile("s_waitcnt lgkmcnt(0)" ::: "memory");
    __builtin_amdgcn_sched_barrier(0);
    __builtin_amdgcn_s_setprio(1);
    #pragma unroll
    for (int m = 0; m < 4; m++)
      #pragma unroll
      for (int n = 0; n < 4; n++)
        acc[m + 4][n] = __builtin_amdgcn_mfma_f32_16x16x32_bf16(bv[n], af[m], acc[m + 4][n], 0, 0, 0);
    __builtin_amdgcn_s_setprio(0);
    __builtin_amdgcn_s_barrier();
    __builtin_amdgcn_sched_barrier(0);

    // ---------------- P2: ks1, m0-3 ----------------
    #pragma unroll
    for (int n = 0; n < 4; n++) bv[n] = *(const bf16x8*)(Bc + (boff[n] ^ 64));
    #pragma unroll
    for (int m = 0; m < 4; m++) af[m] = *(const bf16x8*)(Ac + (aoff[m] ^ 64));
    if (pf) {
      gl_lds16(A  + (size_t)arow[2] * Kd + kb + acol[2], &nA[(tid + 1024) * 8]);
      gl_lds16(Bp + (size_t)brow[2] * Kd + kb + acol[2], &nB[(tid + 1024) * 8]);
    }
    __builtin_amdgcn_s_barrier();
    asm volatile("s_waitcnt lgkmcnt(0)" ::: "memory");
    __builtin_amdgcn_sched_barrier(0);
    __builtin_amdgcn_s_setprio(1);
    #pragma unroll
    for (int m = 0; m < 4; m++)
      #pragma unroll
      for (int n = 0; n < 4; n++)
        acc[m][n] = __builtin_amdgcn_mfma_f32_16x16x32_bf16(bv[n], af[m], acc[m][n], 0, 0, 0);
    __builtin_amdgcn_s_setprio(0);
    __builtin_amdgcn_s_barrier();
    __builtin_amdgcn_sched_barrier(0);

    // ---------------- P3: ks1, m4-7 (bv reused) ----------------
    #pragma unroll
    for (int m = 0; m < 4; m++) af[m] = *(const bf16x8*)(Ac + (aoff[m + 4] ^ 64));
    if (pf) {
      gl_lds16(A  + (size_t)arow[3] * Kd + kb + acol[3], &nA[(tid + 1536) * 8]);
      gl_lds16(Bp + (size_t)brow[3] * Kd + kb + acol[3], &nB[(tid + 1536) * 8]);
    }
    __builtin_amdgcn_s_barrier();
    asm volatile("s_waitcnt lgkmcnt(0)" ::: "memory");
    __builtin_amdgcn_sched_barrier(0);
    __builtin_amdgcn_s_setprio(1);
    #pragma unroll
    for (int m = 0; m < 4; m++)
      #pragma unroll
      for (int n = 0; n < 4; n++)
        acc[m + 4][n] = __builtin_amdgcn_mfma_f32_16x16x32_bf16(bv[n], af[m], acc[m + 4][n], 0, 0, 0);
    __builtin_amdgcn_s_setprio(0);
    __builtin_amdgcn_s_barrier();    // all reads of buf[cur] done before next iter's stages
    __builtin_amdgcn_sched_barrier(0);

    cur ^= 1;
  }

  // epilogue: lane holds out(row = bm*256 + wm*128 + m*16 + (l&15), cols c0[n]..c0[n]+3)
  f32x4 biasv[4];
  int   c0[4];
  #pragma unroll
  for (int n = 0; n < 4; n++) {
    c0[n] = bn * 256 + wn * 64 + n * 16 + ((l >> 4) << 2);
    biasv[n] = *(const f32x4*)(bp + c0[n]);
  }
  #pragma unroll
  for (int m = 0; m < 8; m++) {
    const int row = bm * 256 + wm * 128 + m * 16 + (l & 15);   // local for MODE>=2
    #pragma unroll
    for (int n = 0; n < 4; n++) {
      f32x4 v = acc[m][n] + biasv[n];
      if (MODE == 0) {
        *(uint2*)((u16*)outp + (size_t)row * N + c0[n]) =
            make_uint2(pkbf(v[0], v[1]), pkbf(v[2], v[3]));
      } else if (MODE == 2) {
        if (row < cnt) {
          #pragma unroll
          for (int r = 0; r < 4; r++)
            v[r] = v[r] * __builtin_amdgcn_rcpf(1.f + __expf(-1.702f * v[r]));  // QuickGELU
          *(uint2*)((u16*)outp + (size_t)(gbase + row) * FFDIM + c0[n]) =
              make_uint2(pkbf(v[0], v[1]), pkbf(v[2], v[3]));
        }
      } else {
        if (row < cnt)
          *(uint2*)((u16*)outp + (size_t)(gbase + row) * DMODEL + c0[n]) =
              make_uint2(pkbf(v[0], v[1]), pkbf(v[2], v[3]));
      }
    }
  }
}

// ------- 128x128x64 out-proj GEMM (2-phase counted vmcnt, small-N out-proj) -------
__global__ __launch_bounds__(256)
void gemm128_op(const u16* __restrict__ A, const u16* __restrict__ Bw,
                int M, int N, int Kd,
                const float* __restrict__ bias, const float* __restrict__ resid,
                float* __restrict__ outp)
{
  __shared__ u16 As[2][128 * 64];
  __shared__ u16 Bs[2][128 * 64];
  const int tid = threadIdx.x;
  const int l   = tid & 63;
  const int w   = tid >> 6;
  const int wm  = w >> 1, wn = w & 1;
  const int bn  = blockIdx.y, bm = blockIdx.x;

  int arow[4], acol[4], brow[4];
  #pragma unroll
  for (int i = 0; i < 4; i++) {
    const int c = tid + 256 * i;
    const int r = c >> 3;
    const int f = (r & 7) ^ ((r >> 3) & 7);
    acol[i] = ((c & 7) ^ f) * 8;
    brow[i] = bn * 128 + r;
    arow[i] = bm * 128 + r;
  }

  f32x4 acc[4][4] = {};
  const int nk = Kd >> 6;
  #pragma unroll
  for (int i = 0; i < 4; i++) {
    gl_lds16(A  + (size_t)arow[i] * Kd + acol[i], &As[0][(i * 256 + w * 64) * 8]);
    gl_lds16(Bw + (size_t)brow[i] * Kd + acol[i], &Bs[0][(i * 256 + w * 64) * 8]);
  }
  int cur = 0;
  for (int kt = 0; kt < nk; kt++) {
    const bool pf = (kt + 1 < nk);
    if (pf) {
      const int kb = (kt + 1) * 64;
      #pragma unroll
      for (int i = 0; i < 4; i++) {
        gl_lds16(A  + (size_t)arow[i] * Kd + kb + acol[i], &As[cur ^ 1][(i * 256 + w * 64) * 8]);
        gl_lds16(Bw + (size_t)brow[i] * Kd + kb + acol[i], &Bs[cur ^ 1][(i * 256 + w * 64) * 8]);
      }
      asm volatile("s_waitcnt vmcnt(8)" ::: "memory");
    } else {
      asm volatile("s_waitcnt vmcnt(0)" ::: "memory");
    }
    __builtin_amdgcn_s_barrier();
    __builtin_amdgcn_sched_barrier(0);
    #pragma unroll
    for (int ks = 0; ks < 2; ks++) {
      bf16x8 af[4], bv[4];
      #pragma unroll
      for (int m = 0; m < 4; m++) {
        const int row = wm * 64 + m * 16 + (l & 15);
        af[m] = *(const bf16x8*)((const char*)&As[cur][0] +
                  ((row * 128 + ks * 64 + (l >> 4) * 16) ^ swz64(row)));
      }
      #pragma unroll
      for (int n = 0; n < 4; n++) {
        const int row = wn * 64 + n * 16 + (l & 15);
        bv[n] = *(const bf16x8*)((const char*)&Bs[cur][0] +
                  ((row * 128 + ks * 64 + (l >> 4) * 16) ^ swz64(row)));
      }
      #pragma unroll
      for (int m = 0; m < 4; m++)
        #pragma unroll
        for (int n = 0; n < 4; n++)
          acc[m][n] = __builtin_amdgcn_mfma_f32_16x16x32_bf16(bv[n], af[m], acc[m][n], 0, 0, 0);
    }
    if (pf) __builtin_amdgcn_s_barrier();
    cur ^= 1;
  }

  f32x4 biasv[4];
  int   c0[4];
  #pragma unroll
  for (int n = 0; n < 4; n++) {
    c0[n] = bn * 128 + wn * 64 + n * 16 + ((l >> 4) << 2);
    biasv[n] = *(const f32x4*)(bias + c0[n]);
  }
  #pragma unroll
  for (int m = 0; m < 4; m++) {
    const int row = bm * 128 + wm * 64 + m * 16 + (l & 15);
    #pragma unroll
    for (int n = 0; n < 4; n++) {
      const size_t o = (size_t)row * N + c0[n];
      f32x4 v = acc[m][n] + biasv[n] + *(const f32x4*)(resid + o);
      *(f32x4*)(outp + o) = v;
    }
  }
}

// ---------------- flash attention: block = (q-tile 64) x (b,h), 4 waves ----------------
__global__ __launch_bounds__(256)
void attn_fwd(const u16* __restrict__ qkv, u16* __restrict__ o)
{
  __shared__ u16 Ksw[64 * 64];        // K tile [key][hd], swizzled
  __shared__ u16 Vt [64 * 64];        // V^T tile [hd][key], swizzled
  __shared__ u16 Pl [4 * 16 * 64];    // per-wave P tile [16 q][64 key], swizzled
  const int tid = threadIdx.x;
  const int l   = tid & 63, w = tid >> 6;
  const int qt  = blockIdx.x;
  const int b_  = blockIdx.y / NHEAD;
  const int hh  = blockIdx.y % NHEAD;

  // Q A-fragments (resident whole kernel)
  const int qrow = qt * 64 + w * 16 + (l & 15);
  const size_t qoff = ((size_t)(qrow * BATCH + b_)) * D3 + hh * HDIM + (l >> 4) * 8;
  const bf16x8 qa0 = *(const bf16x8*)&qkv[qoff];
  const bf16x8 qa1 = *(const bf16x8*)&qkv[qoff + 32];

  f32x4 oacc[4] = {};
  float m_[4], l_[4];
  #pragma unroll
  for (int r = 0; r < 4; r++) { m_[r] = -1e30f; l_[r] = 0.f; }

  u16* Pw = Pl + w * 1024;
  const int pswz = swz64(l & 15);

  for (int kt = 0; kt < 16; kt++) {
    // ---- stage K (linear rows, swizzled) and V (transposed scatter, swizzled) ----
    #pragma unroll
    for (int i = 0; i < 2; i++) {
      const int c = tid + 256 * i;
      const int key = c >> 3, dimb = (c & 7) * 8;
      const size_t gb = ((size_t)((kt * 64 + key) * BATCH + b_)) * D3 + hh * HDIM + dimb;
      const bf16x8 kd = *(const bf16x8*)&qkv[gb + DMODEL];
      const bf16x8 vd = *(const bf16x8*)&qkv[gb + 2 * DMODEL];
      *(bf16x8*)((char*)Ksw + ((key * 128 + dimb * 2) ^ swz64(key))) = kd;
      #pragma unroll
      for (int j = 0; j < 8; j++) {
        const int dim = dimb + j;
        *(u16*)((char*)Vt + ((dim * 128 + key * 2) ^ swz64(dim))) = (u16)vd[j];
      }
    }
    __syncthreads();

    // ---- S = Q K^T ----
    f32x4 sc[4] = {};
    #pragma unroll
    for (int kb2 = 0; kb2 < 4; kb2++) {
      const int key = kb2 * 16 + (l & 15);
      const int ksz = swz64(key);
      #pragma unroll
      for (int ks = 0; ks < 2; ks++) {
        const bf16x8 kf = *(const bf16x8*)((char*)Ksw +
            ((key * 128 + (ks * 32 + (l >> 4) * 8) * 2) ^ ksz));
        sc[kb2] = __builtin_amdgcn_mfma_f32_16x16x32_bf16(ks ? qa1 : qa0, kf, sc[kb2], 0, 0, 0);
      }
    }
    #pragma unroll
    for (int kb2 = 0; kb2 < 4; kb2++)
      #pragma unroll
      for (int r = 0; r < 4; r++) sc[kb2][r] *= 0.125f;   // hd^-0.5

    // ---- online softmax (rows live in 16-lane groups) ----
    float nm[4], corr[4], ps[4];
    #pragma unroll
    for (int r = 0; r < 4; r++) {
      float pm = fmaxf(fmaxf(sc[0][r], sc[1][r]), fmaxf(sc[2][r], sc[3][r]));
      pm = fmaxf(pm, __shfl_xor(pm, 1));
      pm = fmaxf(pm, __shfl_xor(pm, 2));
      pm = fmaxf(pm, __shfl_xor(pm, 4));
      pm = fmaxf(pm, __shfl_xor(pm, 8));
      nm[r]   = fmaxf(m_[r], pm);
      corr[r] = __expf(m_[r] - nm[r]);
      m_[r]   = nm[r];
      ps[r]   = 0.f;
    }
    #pragma unroll
    for (int kb2 = 0; kb2 < 4; kb2++) {
      #pragma unroll
      for (int r = 0; r < 4; r++) {
        const float p = __expf(sc[kb2][r] - nm[r]);
        ps[r] += p;
        const int prow = (l >> 4) * 4 + r;
        const int pcol = kb2 * 16 + (l & 15);
        *(u16*)((char*)Pw + ((prow * 128 + pcol * 2) ^ swz64(prow))) = f2bf(p);
      }
    }
    #pragma unroll
    for (int r = 0; r < 4; r++) {
      float s = ps[r];
      s += __shfl_xor(s, 1); s += __shfl_xor(s, 2);
      s += __shfl_xor(s, 4); s += __shfl_xor(s, 8);
      l_[r] = l_[r] * corr[r] + s;
      #pragma unroll
      for (int ob = 0; ob < 4; ob++) oacc[ob][r] *= corr[r];
    }

    // ---- O += P V  (P read back as A-frags; same-wave LDS is in-order) ----
    #pragma unroll
    for (int ob = 0; ob < 4; ob++) {
      const int dim = ob * 16 + (l & 15);
      const int vsz = swz64(dim);
      #pragma unroll
      for (int ks = 0; ks < 2; ks++) {
        const int kko = (ks * 32 + (l >> 4) * 8) * 2;
        const bf16x8 pf = *(const bf16x8*)((char*)Pw + (((l & 15) * 128 + kko) ^ pswz));
        const bf16x8 vf = *(const bf16x8*)((char*)Vt + ((dim * 128 + kko) ^ vsz));
        oacc[ob] = __builtin_amdgcn_mfma_f32_16x16x32_bf16(pf, vf, oacc[ob], 0, 0, 0);
      }
    }
    __syncthreads();
  }

  #pragma unroll
  for (int r = 0; r < 4; r++) {
    const float inv = 1.f / l_[r];
    const int qs = qt * 64 + w * 16 + (l >> 4) * 4 + r;
    #pragma unroll
    for (int ob = 0; ob < 4; ob++)
      o[((size_t)(qs * BATCH + b_)) * DMODEL + hh * HDIM + ob * 16 + (l & 15)] =
          f2bf(oacc[ob][r] * inv);
  }
}

// ---------------- final combine: out = x1 + w0*eout[p0] + w1*eout[p1] ----------------
__global__ __launch_bounds__(192)
void moe_combine(const float* __restrict__ x1, const u16* __restrict__ eout,
                 const int* __restrict__ posmap, const float* __restrict__ selw,
                 float* __restrict__ out)
{
  const int t = blockIdx.x, j = threadIdx.x;   // 192 threads * 4 = 768
  const int p0 = posmap[2 * t], p1 = posmap[2 * t + 1];
  const float w0 = selw[2 * t], w1 = selw[2 * t + 1];
  const float4 xv = ((const float4*)(x1 + (size_t)t * DMODEL))[j];
  const s16x4 a = ((const s16x4*)(eout + (size_t)p0 * DMODEL))[j];
  const s16x4 c = ((const s16x4*)(eout + (size_t)p1 * DMODEL))[j];
  float4 r;
  r.x = xv.x + w0 * bf2f((u16)a[0]) + w1 * bf2f((u16)c[0]);
  r.y = xv.y + w0 * bf2f((u16)a[1]) + w1 * bf2f((u16)c[1]);
  r.z = xv.z + w0 * bf2f((u16)a[2]) + w1 * bf2f((u16)c[2]);
  r.w = xv.w + w0 * bf2f((u16)a[3]) + w1 * bf2f((u16)c[3]);
  ((float4*)(out + (size_t)t * DMODEL))[j] = r;
}

// ---------------- workspace layout (needs ws_size >= ~255 MB) ----------------
#define MB (1ull << 20)
static const size_t OFF_H    = 0;                 // 12.6M  h bf16   (dead after QKV gemm)
static const size_t OFF_QKV  = 16 * MB;           // 37.75M          (dead after attention)
static const size_t OFF_O    = 54 * MB;           // 12.6M           (dead after out-proj)
static const size_t OFF_IPW  = 67 * MB;           // 3.54M           (dead after QKV gemm)
static const size_t OFF_OPW  = 71 * MB;           // 1.18M           (dead after out-proj)
static const size_t OFF_MID  = 0;                 // 100.7M mid bf16 (aliases all of the above)
static const size_t OFF_X1   = 101 * MB;          // 25.2M  x1 f32
static const size_t OFF_H2   = 127 * MB;          // 12.6M  h2 bf16
static const size_t OFF_W1T  = 140 * MB;          // 37.75M w1^T bf16
static const size_t OFF_W2T  = 178 * MB;          // 37.75M w2^T bf16
static const size_t OFF_EOUT = 216 * MB;          // 25.2M  expert out bf16
static const size_t OFF_SELW = 242 * MB;                    // T*2 f32
static const size_t OFF_PERM = 242 * MB + (1 << 16);        // NGATH i32
static const size_t OFF_POS  = 242 * MB + (2 << 16);        // T*2 i32
static const size_t OFF_SELI = 242 * MB + (3 << 16);        // T*2 i32
static const size_t OFF_BCNT = 242 * MB + (4 << 16);        // 32*8 i32
static const size_t OFF_BBASE= 242 * MB + (4 << 16) + 4096; // 32*8 i32
static const size_t OFF_OFFS = 242 * MB + (4 << 16) + 8192; // 9 i32
static const size_t OFF_WL   = 242 * MB + (5 << 16);        // work list i32
static const size_t OFF_NW   = 242 * MB + (5 << 16) + 1024; // 1 i32

extern "C" void kernel_launch(void* const* d_in, const int* in_sizes, int n_in,
                              void* d_out, int out_size, void* d_ws, size_t ws_size,
                              hipStream_t stream)
{
  const float* x     = (const float*)d_in[0];
  const float* ln1w  = (const float*)d_in[1];
  const float* ln1b  = (const float*)d_in[2];
  const float* ipw_f = (const float*)d_in[3];
  const float* ipb   = (const float*)d_in[4];
  const float* opw_f = (const float*)d_in[5];
  const float* opb   = (const float*)d_in[6];
  const float* ln2w  = (const float*)d_in[7];
  const float* ln2b  = (const float*)d_in[8];
  const float* gatew = (const float*)d_in[9];
  const float* w1    = (const float*)d_in[10];
  const float* b1    = (const float*)d_in[11];
  const float* w2    = (const float*)d_in[12];
  const float* b2    = (const float*)d_in[13];

  char* ws = (char*)d_ws;
  u16*   h    = (u16*)(ws + OFF_H);
  u16*   qkv  = (u16*)(ws + OFF_QKV);
  u16*   ob   = (u16*)(ws + OFF_O);
  u16*   ipw  = (u16*)(ws + OFF_IPW);
  u16*   opw  = (u16*)(ws + OFF_OPW);
  u16*   mid  = (u16*)(ws + OFF_MID);
  float* x1   = (float*)(ws + OFF_X1);
  u16*   h2   = (u16*)(ws + OFF_H2);
  u16*   w1t  = (u16*)(ws + OFF_W1T);
  u16*   w2t  = (u16*)(ws + OFF_W2T);
  u16*   eout = (u16*)(ws + OFF_EOUT);
  float* selw = (float*)(ws + OFF_SELW);
  int*   perm = (int*)(ws + OFF_PERM);
  int*   posm = (int*)(ws + OFF_POS);
  int*   seli = (int*)(ws + OFF_SELI);
  int*   bcnt = (int*)(ws + OFF_BCNT);
  int*   bbas = (int*)(ws + OFF_BBASE);
  int*   offs = (int*)(ws + OFF_OFFS);
  int*   wl   = (int*)(ws + OFF_WL);
  int*   nwork= (int*)(ws + OFF_NW);
  float* outx  = (float*)d_out;
  float* outlg = outx + (size_t)NTOK * DMODEL;

  // allow 128 KB dynamic LDS on the big-tile GEMMs (idempotent; host-side, capture-safe)
  static const int LDS_BYTES = 131072;
  (void)hipFuncSetAttribute((const void*)gemm256<0>, hipFuncAttributeMaxDynamicSharedMemorySize, LDS_BYTES);
  (void)hipFuncSetAttribute((const void*)gemm256<2>, hipFuncAttributeMaxDynamicSharedMemorySize, LDS_BYTES);
  (void)hipFuncSetAttribute((const void*)gemm256<3>, hipFuncAttributeMaxDynamicSharedMemorySize, LDS_BYTES);

  // 1. weight conversions (must redo every call: deterministic, no caching)
  cvt_bf16<<<(D3 * DMODEL) / 1024, 256, 0, stream>>>(ipw_f, ipw, D3 * DMODEL);
  cvt_bf16<<<(DMODEL * DMODEL) / 1024, 256, 0, stream>>>(opw_f, opw, DMODEL * DMODEL);
  transpose_cvt<<<dim3(FFDIM / 32, DMODEL / 32, NEXP), dim3(32, 8), 0, stream>>>(w1, w1t, DMODEL, FFDIM);
  transpose_cvt<<<dim3(DMODEL / 32, FFDIM / 32, NEXP), dim3(32, 8), 0, stream>>>(w2, w2t, FFDIM, DMODEL);

  // 2. attention path
  ln_fwd<<<NTOK, 256, 0, stream>>>(x, ln1w, ln1b, h);
  gemm256<0><<<dim3(NTOK / 256, D3 / 256, 1), 512, LDS_BYTES, stream>>>(
      h, ipw, NTOK, D3, DMODEL, ipb, qkv, nullptr, nullptr, nullptr, nullptr);
  attn_fwd<<<dim3(S_LEN / 64, BATCH * NHEAD), 256, 0, stream>>>(qkv, ob);
  gemm128_op<<<dim3(NTOK / 128, DMODEL / 128, 1), 256, 0, stream>>>(
      ob, opw, NTOK, DMODEL, DMODEL, opb, x, x1);

  // 3. routing
  ln2_gate<<<NTOK, 256, 0, stream>>>(x1, ln2w, ln2b, gatew, h2, outlg, selw, seli);
  route_count<<<32, 256, 0, stream>>>(seli, bcnt);
  route_scan<<<1, 64, 0, stream>>>(bcnt, offs, bbas, wl, nwork);
  route_place<<<32, 256, 0, stream>>>(seli, bbas, perm, posm);

  // 4. expert FFNs on compacted work list (live 256-row tiles only)
  gemm256<2><<<dim3(MAXWL, FFDIM / 256, 1), 512, LDS_BYTES, stream>>>(
      h2, w1t, NGATH, FFDIM, DMODEL, b1, mid, perm, offs, wl, nwork);
  gemm256<3><<<dim3(MAXWL, DMODEL / 256, 1), 512, LDS_BYTES, stream>>>(
      mid, w2t, NGATH, DMODEL, FFDIM, b2, eout, nullptr, offs, wl, nwork);

  // 5. combine + residual
  moe_combine<<<NTOK, 192, 0, stream>>>(x1, eout, posm, selw, outx);
}

// Round 11
// 540.020 us; speedup vs baseline: 1.0374x; 1.0374x over previous
//
#include <hip/hip_runtime.h>
#include <stdint.h>

#define S_LEN  1024
#define BATCH  8
#define DMODEL 768
#define NHEAD  12
#define HDIM   64
#define NEXP   8
#define FFDIM  3072
#define NTOK   8192     // S*B
#define D3     2304     // 3*D
#define NGATH  16384    // NTOK * topk(2)
#define MAXWL  136      // max live 128-row tiles across experts

typedef unsigned short u16;
typedef unsigned int   u32;
typedef __attribute__((ext_vector_type(8))) short bf16x8;
typedef __attribute__((ext_vector_type(4))) float f32x4;
typedef __attribute__((ext_vector_type(4))) short s16x4;

__device__ __forceinline__ u16 f2bf(float f){
  u32 x = __float_as_uint(f);
  x += 0x7fffu + ((x >> 16) & 1u);          // RNE
  return (u16)(x >> 16);
}
__device__ __forceinline__ float bf2f(u16 u){
  return __uint_as_float(((u32)u) << 16);
}
__device__ __forceinline__ u32 pkbf(float a, float b){   // lo=bf(a), hi=bf(b)
  u32 d; asm("v_cvt_pk_bf16_f32 %0, %1, %2" : "=v"(d) : "v"(a), "v"(b)); return d;
}
__device__ __forceinline__ void gl_lds16(const void* g, void* l){
  __builtin_amdgcn_global_load_lds(
      (const __attribute__((address_space(1))) u32*)(uintptr_t)g,
      (__attribute__((address_space(3))) u32*)(u32)(uintptr_t)l,
      16, 0, 0);
}
// XOR swizzle for 128B-stride row-major bf16 LDS tiles (G4 fix), 16B-chunk preserving
__device__ __forceinline__ int swz64(int r){ return ((r & 7) ^ ((r >> 3) & 7)) << 4; }

// bijective XCD-aware remap (m204): orig < nwg -> each XCD (orig%8) owns a contiguous
// chunk of the work enumeration. Perf-only heuristic (assumes dispatch XCD = orig%8).
__device__ __forceinline__ int xcd_swz(int orig, int nwg){
  const int q = nwg >> 3, r = nwg & 7;
  const int xcd = orig & 7, loc = orig >> 3;
  return (xcd < r ? xcd * (q + 1) : r * (q + 1) + (xcd - r) * q) + loc;
}

// ---------------- elementwise fp32 -> bf16 convert ----------------
__global__ __launch_bounds__(256)
void cvt_bf16(const float* __restrict__ in, u16* __restrict__ out, int n)
{
  int i = (blockIdx.x * 256 + threadIdx.x) * 4;
  if (i + 3 < n) {
    float4 v = *(const float4*)(in + i);
    out[i]     = f2bf(v.x);
    out[i + 1] = f2bf(v.y);
    out[i + 2] = f2bf(v.z);
    out[i + 3] = f2bf(v.w);
  }
}

// ------- transpose + convert v2: 64x64 tile, float4 loads, padded LDS, uint2 stores -------
// in[rows][cols] f32 -> out[cols][rows] bf16
__global__ __launch_bounds__(256)
void transpose_cvt(const float* __restrict__ in, u16* __restrict__ out, int rows, int cols)
{
  __shared__ float tile[64][65];
  const size_t eo = (size_t)blockIdx.z * rows * cols;
  in  += eo; out += eo;
  const int bx = blockIdx.x * 64;   // input col base
  const int by = blockIdx.y * 64;   // input row base
  const int tid = threadIdx.x;
  #pragma unroll
  for (int i = 0; i < 4; i++) {
    const int c = tid + 256 * i;            // 1024 float4 chunks
    const int r = c >> 4, c4 = (c & 15) * 4;
    const float4 v = *(const float4*)(in + (size_t)(by + r) * cols + bx + c4);
    tile[r][c4] = v.x; tile[r][c4 + 1] = v.y; tile[r][c4 + 2] = v.z; tile[r][c4 + 3] = v.w;
  }
  __syncthreads();
  #pragma unroll
  for (int i = 0; i < 4; i++) {
    const int c = tid + 256 * i;
    const int orow = c >> 4, r4 = (c & 15) * 4;   // orow = input col; r4 = input row base
    uint2 p;
    p.x = pkbf(tile[r4][orow],     tile[r4 + 1][orow]);
    p.y = pkbf(tile[r4 + 2][orow], tile[r4 + 3][orow]);
    *(uint2*)(out + (size_t)(bx + orow) * rows + by + r4) = p;
  }
}

// ---------------- LayerNorm (row = 768) -> bf16 ----------------
__global__ __launch_bounds__(256)
void ln_fwd(const float* __restrict__ x, const float* __restrict__ w, const float* __restrict__ b,
            u16* __restrict__ out)
{
  const int t = blockIdx.x, tid = threadIdx.x;
  const float* xr = x + (size_t)t * DMODEL;
  const float v0 = xr[tid], v1 = xr[tid + 256], v2 = xr[tid + 512];
  float s = v0 + v1 + v2, ss = v0 * v0 + v1 * v1 + v2 * v2;
  #pragma unroll
  for (int d = 1; d < 64; d <<= 1) { s += __shfl_xor(s, d); ss += __shfl_xor(ss, d); }
  __shared__ float rs[4], rq[4];
  if ((tid & 63) == 0) { rs[tid >> 6] = s; rq[tid >> 6] = ss; }
  __syncthreads();
  s  = rs[0] + rs[1] + rs[2] + rs[3];
  ss = rq[0] + rq[1] + rq[2] + rq[3];
  const float mean = s * (1.f / DMODEL);
  const float rstd = rsqrtf(ss * (1.f / DMODEL) - mean * mean + 1e-5f);
  u16* orow = out + (size_t)t * DMODEL;
  orow[tid]       = f2bf((v0 - mean) * rstd * w[tid]       + b[tid]);
  orow[tid + 256] = f2bf((v1 - mean) * rstd * w[tid + 256] + b[tid + 256]);
  orow[tid + 512] = f2bf((v2 - mean) * rstd * w[tid + 512] + b[tid + 512]);
}

// ---------------- LN2 + gate logits + top-2 routing ----------------
__global__ __launch_bounds__(256)
void ln2_gate(const float* __restrict__ x1, const float* __restrict__ w, const float* __restrict__ b,
              const float* __restrict__ gate_w, u16* __restrict__ h2,
              float* __restrict__ logits, float* __restrict__ selw, int* __restrict__ seli)
{
  const int t = blockIdx.x, tid = threadIdx.x;
  const float* xr = x1 + (size_t)t * DMODEL;
  const float v0 = xr[tid], v1 = xr[tid + 256], v2 = xr[tid + 512];
  float s = v0 + v1 + v2, ss = v0 * v0 + v1 * v1 + v2 * v2;
  #pragma unroll
  for (int d = 1; d < 64; d <<= 1) { s += __shfl_xor(s, d); ss += __shfl_xor(ss, d); }
  __shared__ float rs[4], rq[4];
  if ((tid & 63) == 0) { rs[tid >> 6] = s; rq[tid >> 6] = ss; }
  __syncthreads();
  s  = rs[0] + rs[1] + rs[2] + rs[3];
  ss = rq[0] + rq[1] + rq[2] + rq[3];
  const float mean = s * (1.f / DMODEL);
  const float rstd = rsqrtf(ss * (1.f / DMODEL) - mean * mean + 1e-5f);
  __shared__ float row[DMODEL];
  const float y0 = (v0 - mean) * rstd * w[tid]       + b[tid];
  const float y1 = (v1 - mean) * rstd * w[tid + 256] + b[tid + 256];
  const float y2 = (v2 - mean) * rstd * w[tid + 512] + b[tid + 512];
  row[tid] = y0; row[tid + 256] = y1; row[tid + 512] = y2;
  u16* hr = h2 + (size_t)t * DMODEL;
  hr[tid] = f2bf(y0); hr[tid + 256] = f2bf(y1); hr[tid + 512] = f2bf(y2);
  __syncthreads();
  __shared__ float lg[NEXP];
  if (tid < 64) {
    const int e = tid >> 3, j = tid & 7;
    const float* gw = gate_w + e * DMODEL;
    float a = 0.f;
    for (int d = j; d < DMODEL; d += 8) a += row[d] * gw[d];
    a += __shfl_xor(a, 1); a += __shfl_xor(a, 2); a += __shfl_xor(a, 4);
    if (j == 0) lg[e] = a;
  }
  __syncthreads();
  if (tid < NEXP) logits[(size_t)t * NEXP + tid] = lg[tid];
  if (tid == 0) {
    int ia = 0, ib = -1;
    float va = -1e30f, vb = -1e30f;
    #pragma unroll
    for (int e = 0; e < NEXP; e++) {
      const float p = lg[e];
      if (p > va)      { vb = va; ib = ia; va = p; ia = e; }
      else if (p > vb) { vb = p; ib = e; }
    }
    const float pb = __expf(vb - va);          // softmax of {va,vb}; full-Z cancels in renorm
    const float inv = 1.f / (1.f + pb);
    selw[2 * t]     = inv;
    selw[2 * t + 1] = pb * inv;
    seli[2 * t]     = ia;
    seli[2 * t + 1] = ib;
  }
}

// ---------------- deterministic token->expert compaction ----------------
__global__ __launch_bounds__(256)
void route_count(const int* __restrict__ seli, int* __restrict__ blkcnt)
{
  __shared__ int c[NEXP];
  const int tid = threadIdx.x;
  if (tid < NEXP) c[tid] = 0;
  __syncthreads();
  const int t = blockIdx.x * 256 + tid;
  atomicAdd(&c[seli[2 * t]], 1);
  atomicAdd(&c[seli[2 * t + 1]], 1);
  __syncthreads();
  if (tid < NEXP) blkcnt[blockIdx.x * NEXP + tid] = c[tid];
}

// also builds the live-tile work list (128-row tiles): wl[i] = (e<<16)|bm_local, nwork[0] = count
__global__ void route_scan(const int* __restrict__ blkcnt, int* __restrict__ offs,
                           int* __restrict__ blkbase, int* __restrict__ wl, int* __restrict__ nwork)
{
  const int tid = threadIdx.x;   // 64 threads
  __shared__ int tot[NEXP];
  __shared__ int off_s[NEXP + 1];
  if (tid < NEXP) {
    int s = 0;
    for (int blk = 0; blk < 32; blk++) s += blkcnt[blk * NEXP + tid];
    tot[tid] = s;
  }
  __syncthreads();
  if (tid == 0) {
    int run = 0;
    for (int e = 0; e < NEXP; e++) { off_s[e] = run; run += tot[e]; }
    off_s[NEXP] = run;
    int nw = 0;
    for (int e = 0; e < NEXP; e++) {
      const int nb = (tot[e] + 127) >> 7;
      for (int i2 = 0; i2 < nb; i2++) wl[nw++] = (e << 16) | i2;
    }
    nwork[0] = nw;
  }
  __syncthreads();
  if (tid <= NEXP) offs[tid] = off_s[tid];
  if (tid < NEXP) {
    int run = off_s[tid];
    for (int blk = 0; blk < 32; blk++) { blkbase[blk * NEXP + tid] = run; run += blkcnt[blk * NEXP + tid]; }
  }
}

__global__ __launch_bounds__(256)
void route_place(const int* __restrict__ seli, const int* __restrict__ blkbase,
                 int* __restrict__ perm, int* __restrict__ posmap)
{
  __shared__ int cnts[2][4][NEXP];
  __shared__ int base[NEXP];
  const int tid = threadIdx.x, l = tid & 63, w = tid >> 6, blk = blockIdx.x;
  const int t = blk * 256 + tid;
  const unsigned long long ltm = (1ull << l) - 1ull;
  int my_e[2], my_r[2];
  my_e[0] = seli[2 * t]; my_e[1] = seli[2 * t + 1];
  my_r[0] = 0; my_r[1] = 0;
  if (tid < NEXP) base[tid] = blkbase[blk * NEXP + tid];
  #pragma unroll
  for (int k = 0; k < 2; k++) {
    #pragma unroll
    for (int ee = 0; ee < NEXP; ee++) {
      const unsigned long long msk = __ballot(my_e[k] == ee);
      if (my_e[k] == ee) my_r[k] = (int)__popcll(msk & ltm);
      if (l == ee) cnts[k][w][ee] = (int)__popcll(msk);
    }
  }
  __syncthreads();
  #pragma unroll
  for (int k = 0; k < 2; k++) {
    const int e = my_e[k];
    int pre = base[e];
    for (int k2 = 0; k2 < 2; k2++)
      for (int w2 = 0; w2 < 4; w2++)
        if (k2 < k || (k2 == k && w2 < w)) pre += cnts[k2][w2][e];
    const int pos = pre + my_r[k];
    perm[pos] = t;
    posmap[2 * t + k] = pos;
  }
}

// ------- 128x128x64 bf16 MFMA GEMM: 2-phase dbuf, counted vmcnt (R7 structure) -------
// + XCD-aware bijective grid swizzle (T1): 1-D grid, bn-major enumeration so each XCD's
// contiguous chunk shares B-panels -> per-XCD L2 working set ~3-5 MB (was 8x replicated).
// Swapped MFMA operands -> vectorized epilogue. LDS swizzled (rule #21 both-sides).
template<int MODE>  // 0=QKV(bf16,+bias) 1=outproj(f32,+bias,+resid) 2=FFN1(gelu,bf16) 3=FFN2(bf16)
__global__ __launch_bounds__(256)
void gemm128(const u16* __restrict__ A, const u16* __restrict__ Bw,
             int M, int N, int Kd,
             const float* __restrict__ bias, const float* __restrict__ resid,
             void* __restrict__ outp,
             const int* __restrict__ perm, const int* __restrict__ offs,
             const int* __restrict__ wl, const int* __restrict__ nwork)
{
  __shared__ u16 As[2][128 * 64];
  __shared__ u16 Bs[2][128 * 64];
  const int tid = threadIdx.x;
  const int l   = tid & 63;
  const int w   = tid >> 6;
  const int wm  = w >> 1, wn = w & 1;

  int gbase = 0, cnt = M, e = 0, bm, bn;
  if (MODE >= 2) {
    const int nw  = nwork[0];
    const int nwg = nw * (N >> 7);
    if ((int)blockIdx.x >= nwg) return;       // compact work list; cheap uniform exit
    const int t = xcd_swz(blockIdx.x, nwg);   // bn-major: t = bn*nw + bmi
    bn = t / nw;
    const int wk = wl[t - bn * nw];
    e  = wk >> 16;
    bm = wk & 0xffff;
    gbase = offs[e];
    cnt   = offs[e + 1] - gbase;
  } else {
    const int nbm = M >> 7;
    const int t = xcd_swz(blockIdx.x, gridDim.x);
    bn = t / nbm;
    bm = t - bn * nbm;
  }
  const u16*   Bp = Bw   + (MODE >= 2 ? (size_t)e * N * Kd : 0);
  const float* bp = bias + (MODE >= 2 ? e * N : 0);

  int arow[4], acol[4], brow[4];
  #pragma unroll
  for (int i = 0; i < 4; i++) {
    const int c = tid + 256 * i;
    const int r = c >> 3;
    const int f = (r & 7) ^ ((r >> 3) & 7);
    acol[i] = ((c & 7) ^ f) * 8;          // pre-swizzled source column (16B chunk)
    brow[i] = bn * 128 + r;
    int g;
    if (MODE == 2)      { int gp = gbase + bm * 128 + r; if (gp > NGATH - 1) gp = NGATH - 1; g = perm[gp]; }
    else if (MODE == 3) { int gp = gbase + bm * 128 + r; if (gp > NGATH - 1) gp = NGATH - 1; g = gp; }
    else                g = bm * 128 + r;
    arow[i] = g;
  }

  f32x4 acc[4][4] = {};
  const int nk = Kd >> 6;

  // prologue: stage tile 0 into buffer 0
  #pragma unroll
  for (int i = 0; i < 4; i++) {
    gl_lds16(A  + (size_t)arow[i] * Kd + acol[i], &As[0][(i * 256 + w * 64) * 8]);
    gl_lds16(Bp + (size_t)brow[i] * Kd + acol[i], &Bs[0][(i * 256 + w * 64) * 8]);
  }

  int cur = 0;
  for (int kt = 0; kt < nk; kt++) {
    const bool pf = (kt + 1 < nk);
    if (pf) {
      const int kb = (kt + 1) * 64;
      #pragma unroll
      for (int i = 0; i < 4; i++) {
        gl_lds16(A  + (size_t)arow[i] * Kd + kb + acol[i], &As[cur ^ 1][(i * 256 + w * 64) * 8]);
        gl_lds16(Bp + (size_t)brow[i] * Kd + kb + acol[i], &Bs[cur ^ 1][(i * 256 + w * 64) * 8]);
      }
      asm volatile("s_waitcnt vmcnt(8)" ::: "memory");   // drain tile kt; leave kt+1 in flight
    } else {
      asm volatile("s_waitcnt vmcnt(0)" ::: "memory");   // last tile: drain all
    }
    __builtin_amdgcn_s_barrier();                        // all waves' stage(kt) complete
    __builtin_amdgcn_sched_barrier(0);                   // no ds_read hoists above (rule 18)

    #pragma unroll
    for (int ks = 0; ks < 2; ks++) {
      bf16x8 af[4], bv[4];
      #pragma unroll
      for (int m = 0; m < 4; m++) {
        const int row = wm * 64 + m * 16 + (l & 15);
        af[m] = *(const bf16x8*)((const char*)&As[cur][0] +
                  ((row * 128 + ks * 64 + (l >> 4) * 16) ^ swz64(row)));
      }
      #pragma unroll
      for (int n = 0; n < 4; n++) {
        const int row = wn * 64 + n * 16 + (l & 15);
        bv[n] = *(const bf16x8*)((const char*)&Bs[cur][0] +
                  ((row * 128 + ks * 64 + (l >> 4) * 16) ^ swz64(row)));
      }
      #pragma unroll
      for (int m = 0; m < 4; m++)
        #pragma unroll
        for (int n = 0; n < 4; n++)
          acc[m][n] = __builtin_amdgcn_mfma_f32_16x16x32_bf16(bv[n], af[m], acc[m][n], 0, 0, 0);
    }
    if (pf) __builtin_amdgcn_s_barrier();   // compute done before next stage overwrites buf
    cur ^= 1;
  }

  // epilogue: lane holds out(row = bm*128 + wm*64 + m*16 + (l&15), cols c0[n]..c0[n]+3)
  f32x4 biasv[4];
  int   c0[4];
  #pragma unroll
  for (int n = 0; n < 4; n++) {
    c0[n] = bn * 128 + wn * 64 + n * 16 + ((l >> 4) << 2);
    biasv[n] = *(const f32x4*)(bp + c0[n]);
  }
  #pragma unroll
  for (int m = 0; m < 4; m++) {
    const int row = bm * 128 + wm * 64 + m * 16 + (l & 15);   // local for MODE>=2
    #pragma unroll
    for (int n = 0; n < 4; n++) {
      f32x4 v = acc[m][n] + biasv[n];
      if (MODE == 0) {
        *(uint2*)((u16*)outp + (size_t)row * N + c0[n]) =
            make_uint2(pkbf(v[0], v[1]), pkbf(v[2], v[3]));
      } else if (MODE == 1) {
        const size_t o = (size_t)row * N + c0[n];
        f32x4 rv = *(const f32x4*)(resid + o);
        v += rv;
        *(f32x4*)((float*)outp + o) = v;
      } else if (MODE == 2) {
        if (row < cnt) {
          #pragma unroll
          for (int r = 0; r < 4; r++)
            v[r] = v[r] * __builtin_amdgcn_rcpf(1.f + __expf(-1.702f * v[r]));  // QuickGELU
          *(uint2*)((u16*)outp + (size_t)(gbase + row) * FFDIM + c0[n]) =
              make_uint2(pkbf(v[0], v[1]), pkbf(v[2], v[3]));
        }
      } else {
        if (row < cnt)
          *(uint2*)((u16*)outp + (size_t)(gbase + row) * DMODEL + c0[n]) =
              make_uint2(pkbf(v[0], v[1]), pkbf(v[2], v[3]));
      }
    }
  }
}

// ---------------- flash attention: 1-D grid + XCD swizzle (KV locality), 4 waves ----------------
__global__ __launch_bounds__(256)
void attn_fwd(const u16* __restrict__ qkv, u16* __restrict__ o)
{
  __shared__ u16 Ksw[64 * 64];        // K tile [key][hd], swizzled
  __shared__ u16 Vt [64 * 64];        // V^T tile [hd][key], swizzled
  __shared__ u16 Pl [4 * 16 * 64];    // per-wave P tile [16 q][64 key], swizzled
  const int tid = threadIdx.x;
  const int l   = tid & 63, w = tid >> 6;
  // bh-major enumeration: blocks sharing (b,h) [= shared 256KB KV] land on the same XCD
  const int tt  = xcd_swz(blockIdx.x, 16 * BATCH * NHEAD);
  const int qt  = tt & 15;
  const int bh  = tt >> 4;
  const int b_  = bh / NHEAD;
  const int hh  = bh % NHEAD;

  // Q A-fragments (resident whole kernel)
  const int qrow = qt * 64 + w * 16 + (l & 15);
  const size_t qoff = ((size_t)(qrow * BATCH + b_)) * D3 + hh * HDIM + (l >> 4) * 8;
  const bf16x8 qa0 = *(const bf16x8*)&qkv[qoff];
  const bf16x8 qa1 = *(const bf16x8*)&qkv[qoff + 32];

  f32x4 oacc[4] = {};
  float m_[4], l_[4];
  #pragma unroll
  for (int r = 0; r < 4; r++) { m_[r] = -1e30f; l_[r] = 0.f; }

  u16* Pw = Pl + w * 1024;
  const int pswz = swz64(l & 15);

  for (int kt = 0; kt < 16; kt++) {
    // ---- stage K (linear rows, swizzled) and V (transposed scatter, swizzled) ----
    #pragma unroll
    for (int i = 0; i < 2; i++) {
      const int c = tid + 256 * i;
      const int key = c >> 3, dimb = (c & 7) * 8;
      const size_t gb = ((size_t)((kt * 64 + key) * BATCH + b_)) * D3 + hh * HDIM + dimb;
      const bf16x8 kd = *(const bf16x8*)&qkv[gb + DMODEL];
      const bf16x8 vd = *(const bf16x8*)&qkv[gb + 2 * DMODEL];
      *(bf16x8*)((char*)Ksw + ((key * 128 + dimb * 2) ^ swz64(key))) = kd;
      #pragma unroll
      for (int j = 0; j < 8; j++) {
        const int dim = dimb + j;
        *(u16*)((char*)Vt + ((dim * 128 + key * 2) ^ swz64(dim))) = (u16)vd[j];
      }
    }
    __syncthreads();

    // ---- S = Q K^T ----
    f32x4 sc[4] = {};
    #pragma unroll
    for (int kb2 = 0; kb2 < 4; kb2++) {
      const int key = kb2 * 16 + (l & 15);
      const int ksz = swz64(key);
      #pragma unroll
      for (int ks = 0; ks < 2; ks++) {
        const bf16x8 kf = *(const bf16x8*)((char*)Ksw +
            ((key * 128 + (ks * 32 + (l >> 4) * 8) * 2) ^ ksz));
        sc[kb2] = __builtin_amdgcn_mfma_f32_16x16x32_bf16(ks ? qa1 : qa0, kf, sc[kb2], 0, 0, 0);
      }
    }
    #pragma unroll
    for (int kb2 = 0; kb2 < 4; kb2++)
      #pragma unroll
      for (int r = 0; r < 4; r++) sc[kb2][r] *= 0.125f;   // hd^-0.5

    // ---- online softmax (rows live in 16-lane groups) ----
    float nm[4], corr[4], ps[4];
    #pragma unroll
    for (int r = 0; r < 4; r++) {
      float pm = fmaxf(fmaxf(sc[0][r], sc[1][r]), fmaxf(sc[2][r], sc[3][r]));
      pm = fmaxf(pm, __shfl_xor(pm, 1));
      pm = fmaxf(pm, __shfl_xor(pm, 2));
      pm = fmaxf(pm, __shfl_xor(pm, 4));
      pm = fmaxf(pm, __shfl_xor(pm, 8));
      nm[r]   = fmaxf(m_[r], pm);
      corr[r] = __expf(m_[r] - nm[r]);
      m_[r]   = nm[r];
      ps[r]   = 0.f;
    }
    #pragma unroll
    for (int kb2 = 0; kb2 < 4; kb2++) {
      #pragma unroll
      for (int r = 0; r < 4; r++) {
        const float p = __expf(sc[kb2][r] - nm[r]);
        ps[r] += p;
        const int prow = (l >> 4) * 4 + r;
        const int pcol = kb2 * 16 + (l & 15);
        *(u16*)((char*)Pw + ((prow * 128 + pcol * 2) ^ swz64(prow))) = f2bf(p);
      }
    }
    #pragma unroll
    for (int r = 0; r < 4; r++) {
      float s = ps[r];
      s += __shfl_xor(s, 1); s += __shfl_xor(s, 2);
      s += __shfl_xor(s, 4); s += __shfl_xor(s, 8);
      l_[r] = l_[r] * corr[r] + s;
      #pragma unroll
      for (int ob = 0; ob < 4; ob++) oacc[ob][r] *= corr[r];
    }

    // ---- O += P V  (P read back as A-frags; same-wave LDS is in-order) ----
    #pragma unroll
    for (int ob = 0; ob < 4; ob++) {
      const int dim = ob * 16 + (l & 15);
      const int vsz = swz64(dim);
      #pragma unroll
      for (int ks = 0; ks < 2; ks++) {
        const int kko = (ks * 32 + (l >> 4) * 8) * 2;
        const bf16x8 pf = *(const bf16x8*)((char*)Pw + (((l & 15) * 128 + kko) ^ pswz));
        const bf16x8 vf = *(const bf16x8*)((char*)Vt + ((dim * 128 + kko) ^ vsz));
        oacc[ob] = __builtin_amdgcn_mfma_f32_16x16x32_bf16(pf, vf, oacc[ob], 0, 0, 0);
      }
    }
    __syncthreads();
  }

  #pragma unroll
  for (int r = 0; r < 4; r++) {
    const float inv = 1.f / l_[r];
    const int qs = qt * 64 + w * 16 + (l >> 4) * 4 + r;
    #pragma unroll
    for (int ob = 0; ob < 4; ob++)
      o[((size_t)(qs * BATCH + b_)) * DMODEL + hh * HDIM + ob * 16 + (l & 15)] =
          f2bf(oacc[ob][r] * inv);
  }
}

// ---------------- final combine: out = x1 + w0*eout[p0] + w1*eout[p1] ----------------
__global__ __launch_bounds__(192)
void moe_combine(const float* __restrict__ x1, const u16* __restrict__ eout,
                 const int* __restrict__ posmap, const float* __restrict__ selw,
                 float* __restrict__ out)
{
  const int t = blockIdx.x, j = threadIdx.x;   // 192 threads * 4 = 768
  const int p0 = posmap[2 * t], p1 = posmap[2 * t + 1];
  const float w0 = selw[2 * t], w1 = selw[2 * t + 1];
  const float4 xv = ((const float4*)(x1 + (size_t)t * DMODEL))[j];
  const s16x4 a = ((const s16x4*)(eout + (size_t)p0 * DMODEL))[j];
  const s16x4 c = ((const s16x4*)(eout + (size_t)p1 * DMODEL))[j];
  float4 r;
  r.x = xv.x + w0 * bf2f((u16)a[0]) + w1 * bf2f((u16)c[0]);
  r.y = xv.y + w0 * bf2f((u16)a[1]) + w1 * bf2f((u16)c[1]);
  r.z = xv.z + w0 * bf2f((u16)a[2]) + w1 * bf2f((u16)c[2]);
  r.w = xv.w + w0 * bf2f((u16)a[3]) + w1 * bf2f((u16)c[3]);
  ((float4*)(out + (size_t)t * DMODEL))[j] = r;
}

// ---------------- workspace layout (needs ws_size >= ~255 MB) ----------------
#define MB (1ull << 20)
static const size_t OFF_H    = 0;                 // 12.6M  h bf16   (dead after QKV gemm)
static const size_t OFF_QKV  = 16 * MB;           // 37.75M          (dead after attention)
static const size_t OFF_O    = 54 * MB;           // 12.6M           (dead after out-proj)
static const size_t OFF_IPW  = 67 * MB;           // 3.54M           (dead after QKV gemm)
static const size_t OFF_OPW  = 71 * MB;           // 1.18M           (dead after out-proj)
static const size_t OFF_MID  = 0;                 // 100.7M mid bf16 (aliases all of the above)
static const size_t OFF_X1   = 101 * MB;          // 25.2M  x1 f32
static const size_t OFF_H2   = 127 * MB;          // 12.6M  h2 bf16
static const size_t OFF_W1T  = 140 * MB;          // 37.75M w1^T bf16
static const size_t OFF_W2T  = 178 * MB;          // 37.75M w2^T bf16
static const size_t OFF_EOUT = 216 * MB;          // 25.2M  expert out bf16
static const size_t OFF_SELW = 242 * MB;                    // T*2 f32
static const size_t OFF_PERM = 242 * MB + (1 << 16);        // NGATH i32
static const size_t OFF_POS  = 242 * MB + (2 << 16);        // T*2 i32
static const size_t OFF_SELI = 242 * MB + (3 << 16);        // T*2 i32
static const size_t OFF_BCNT = 242 * MB + (4 << 16);        // 32*8 i32
static const size_t OFF_BBASE= 242 * MB + (4 << 16) + 4096; // 32*8 i32
static const size_t OFF_OFFS = 242 * MB + (4 << 16) + 8192; // 9 i32
static const size_t OFF_WL   = 242 * MB + (5 << 16);        // work list i32
static const size_t OFF_NW   = 242 * MB + (5 << 16) + 1024; // 1 i32

extern "C" void kernel_launch(void* const* d_in, const int* in_sizes, int n_in,
                              void* d_out, int out_size, void* d_ws, size_t ws_size,
                              hipStream_t stream)
{
  const float* x     = (const float*)d_in[0];
  const float* ln1w  = (const float*)d_in[1];
  const float* ln1b  = (const float*)d_in[2];
  const float* ipw_f = (const float*)d_in[3];
  const float* ipb   = (const float*)d_in[4];
  const float* opw_f = (const float*)d_in[5];
  const float* opb   = (const float*)d_in[6];
  const float* ln2w  = (const float*)d_in[7];
  const float* ln2b  = (const float*)d_in[8];
  const float* gatew = (const float*)d_in[9];
  const float* w1    = (const float*)d_in[10];
  const float* b1    = (const float*)d_in[11];
  const float* w2    = (const float*)d_in[12];
  const float* b2    = (const float*)d_in[13];

  char* ws = (char*)d_ws;
  u16*   h    = (u16*)(ws + OFF_H);
  u16*   qkv  = (u16*)(ws + OFF_QKV);
  u16*   ob   = (u16*)(ws + OFF_O);
  u16*   ipw  = (u16*)(ws + OFF_IPW);
  u16*   opw  = (u16*)(ws + OFF_OPW);
  u16*   mid  = (u16*)(ws + OFF_MID);
  float* x1   = (float*)(ws + OFF_X1);
  u16*   h2   = (u16*)(ws + OFF_H2);
  u16*   w1t  = (u16*)(ws + OFF_W1T);
  u16*   w2t  = (u16*)(ws + OFF_W2T);
  u16*   eout = (u16*)(ws + OFF_EOUT);
  float* selw = (float*)(ws + OFF_SELW);
  int*   perm = (int*)(ws + OFF_PERM);
  int*   posm = (int*)(ws + OFF_POS);
  int*   seli = (int*)(ws + OFF_SELI);
  int*   bcnt = (int*)(ws + OFF_BCNT);
  int*   bbas = (int*)(ws + OFF_BBASE);
  int*   offs = (int*)(ws + OFF_OFFS);
  int*   wl   = (int*)(ws + OFF_WL);
  int*   nwork= (int*)(ws + OFF_NW);
  float* outx  = (float*)d_out;
  float* outlg = outx + (size_t)NTOK * DMODEL;

  // 1. weight conversions (must redo every call: deterministic, no caching)
  cvt_bf16<<<(D3 * DMODEL) / 1024, 256, 0, stream>>>(ipw_f, ipw, D3 * DMODEL);
  cvt_bf16<<<(DMODEL * DMODEL) / 1024, 256, 0, stream>>>(opw_f, opw, DMODEL * DMODEL);
  transpose_cvt<<<dim3(FFDIM / 64, DMODEL / 64, NEXP), 256, 0, stream>>>(w1, w1t, DMODEL, FFDIM);
  transpose_cvt<<<dim3(DMODEL / 64, FFDIM / 64, NEXP), 256, 0, stream>>>(w2, w2t, FFDIM, DMODEL);

  // 2. attention path
  ln_fwd<<<NTOK, 256, 0, stream>>>(x, ln1w, ln1b, h);
  gemm128<0><<<(NTOK / 128) * (D3 / 128), 256, 0, stream>>>(
      h, ipw, NTOK, D3, DMODEL, ipb, nullptr, qkv, nullptr, nullptr, nullptr, nullptr);
  attn_fwd<<<(S_LEN / 64) * BATCH * NHEAD, 256, 0, stream>>>(qkv, ob);
  gemm128<1><<<(NTOK / 128) * (DMODEL / 128), 256, 0, stream>>>(
      ob, opw, NTOK, DMODEL, DMODEL, opb, x, x1, nullptr, nullptr, nullptr, nullptr);

  // 3. routing
  ln2_gate<<<NTOK, 256, 0, stream>>>(x1, ln2w, ln2b, gatew, h2, outlg, selw, seli);
  route_count<<<32, 256, 0, stream>>>(seli, bcnt);
  route_scan<<<1, 64, 0, stream>>>(bcnt, offs, bbas, wl, nwork);
  route_place<<<32, 256, 0, stream>>>(seli, bbas, perm, posm);

  // 4. expert FFNs on compacted work list (live 128-row tiles only)
  gemm128<2><<<MAXWL * (FFDIM / 128), 256, 0, stream>>>(
      h2, w1t, NGATH, FFDIM, DMODEL, b1, nullptr, mid, perm, offs, wl, nwork);
  gemm128<3><<<MAXWL * (DMODEL / 128), 256, 0, stream>>>(
      mid, w2t, NGATH, DMODEL, FFDIM, b2, nullptr, eout, nullptr, offs, wl, nwork);

  // 5. combine + residual
  moe_combine<<<NTOK, 192, 0, stream>>>(x1, eout, posm, selw, outx);
}

// Round 12
// 525.585 us; speedup vs baseline: 1.0659x; 1.0275x over previous
//
#include <hip/hip_runtime.h>
#include <stdint.h>

#define S_LEN  1024
#define BATCH  8
#define DMODEL 768
#define NHEAD  12
#define HDIM   64
#define NEXP   8
#define FFDIM  3072
#define NTOK   8192     // S*B
#define D3     2304     // 3*D
#define NGATH  16384    // NTOK * topk(2)
#define MAXWL  136      // max live 128-row tiles across experts

typedef unsigned short u16;
typedef unsigned int   u32;
typedef __attribute__((ext_vector_type(8))) short bf16x8;
typedef __attribute__((ext_vector_type(4))) float f32x4;
typedef __attribute__((ext_vector_type(4))) short s16x4;

__device__ __forceinline__ u16 f2bf(float f){
  u32 x = __float_as_uint(f);
  x += 0x7fffu + ((x >> 16) & 1u);          // RNE
  return (u16)(x >> 16);
}
__device__ __forceinline__ float bf2f(u16 u){
  return __uint_as_float(((u32)u) << 16);
}
__device__ __forceinline__ u32 pkbf(float a, float b){   // lo=bf(a), hi=bf(b)
  u32 d; asm("v_cvt_pk_bf16_f32 %0, %1, %2" : "=v"(d) : "v"(a), "v"(b)); return d;
}
__device__ __forceinline__ void gl_lds16(const void* g, void* l){
  __builtin_amdgcn_global_load_lds(
      (const __attribute__((address_space(1))) u32*)(uintptr_t)g,
      (__attribute__((address_space(3))) u32*)(u32)(uintptr_t)l,
      16, 0, 0);
}
// XOR swizzle for 128B-stride row-major bf16 LDS tiles (G4 fix), 16B-chunk preserving
__device__ __forceinline__ int swz64(int r){ return ((r & 7) ^ ((r >> 3) & 7)) << 4; }

// bijective XCD-aware remap (m204): orig < nwg -> each XCD (orig%8) owns a contiguous
// chunk of the work enumeration. Perf-only heuristic (assumes dispatch XCD = orig%8).
__device__ __forceinline__ int xcd_swz(int orig, int nwg){
  const int q = nwg >> 3, r = nwg & 7;
  const int xcd = orig & 7, loc = orig >> 3;
  return (xcd < r ? xcd * (q + 1) : r * (q + 1) + (xcd - r) * q) + loc;
}

// ---------------- elementwise fp32 -> bf16 convert ----------------
__global__ __launch_bounds__(256)
void cvt_bf16(const float* __restrict__ in, u16* __restrict__ out, int n)
{
  int i = (blockIdx.x * 256 + threadIdx.x) * 4;
  if (i + 3 < n) {
    float4 v = *(const float4*)(in + i);
    out[i]     = f2bf(v.x);
    out[i + 1] = f2bf(v.y);
    out[i + 2] = f2bf(v.z);
    out[i + 3] = f2bf(v.w);
  }
}

// ------- transpose + convert v2: 64x64 tile, float4 loads, padded LDS, uint2 stores -------
// in[rows][cols] f32 -> out[cols][rows] bf16
__global__ __launch_bounds__(256)
void transpose_cvt(const float* __restrict__ in, u16* __restrict__ out, int rows, int cols)
{
  __shared__ float tile[64][65];
  const size_t eo = (size_t)blockIdx.z * rows * cols;
  in  += eo; out += eo;
  const int bx = blockIdx.x * 64;   // input col base
  const int by = blockIdx.y * 64;   // input row base
  const int tid = threadIdx.x;
  #pragma unroll
  for (int i = 0; i < 4; i++) {
    const int c = tid + 256 * i;            // 1024 float4 chunks
    const int r = c >> 4, c4 = (c & 15) * 4;
    const float4 v = *(const float4*)(in + (size_t)(by + r) * cols + bx + c4);
    tile[r][c4] = v.x; tile[r][c4 + 1] = v.y; tile[r][c4 + 2] = v.z; tile[r][c4 + 3] = v.w;
  }
  __syncthreads();
  #pragma unroll
  for (int i = 0; i < 4; i++) {
    const int c = tid + 256 * i;
    const int orow = c >> 4, r4 = (c & 15) * 4;   // orow = input col; r4 = input row base
    uint2 p;
    p.x = pkbf(tile[r4][orow],     tile[r4 + 1][orow]);
    p.y = pkbf(tile[r4 + 2][orow], tile[r4 + 3][orow]);
    *(uint2*)(out + (size_t)(bx + orow) * rows + by + r4) = p;
  }
}

// ---------------- LayerNorm (row = 768) -> bf16 ----------------
__global__ __launch_bounds__(256)
void ln_fwd(const float* __restrict__ x, const float* __restrict__ w, const float* __restrict__ b,
            u16* __restrict__ out)
{
  const int t = blockIdx.x, tid = threadIdx.x;
  const float* xr = x + (size_t)t * DMODEL;
  const float v0 = xr[tid], v1 = xr[tid + 256], v2 = xr[tid + 512];
  float s = v0 + v1 + v2, ss = v0 * v0 + v1 * v1 + v2 * v2;
  #pragma unroll
  for (int d = 1; d < 64; d <<= 1) { s += __shfl_xor(s, d); ss += __shfl_xor(ss, d); }
  __shared__ float rs[4], rq[4];
  if ((tid & 63) == 0) { rs[tid >> 6] = s; rq[tid >> 6] = ss; }
  __syncthreads();
  s  = rs[0] + rs[1] + rs[2] + rs[3];
  ss = rq[0] + rq[1] + rq[2] + rq[3];
  const float mean = s * (1.f / DMODEL);
  const float rstd = rsqrtf(ss * (1.f / DMODEL) - mean * mean + 1e-5f);
  u16* orow = out + (size_t)t * DMODEL;
  orow[tid]       = f2bf((v0 - mean) * rstd * w[tid]       + b[tid]);
  orow[tid + 256] = f2bf((v1 - mean) * rstd * w[tid + 256] + b[tid + 256]);
  orow[tid + 512] = f2bf((v2 - mean) * rstd * w[tid + 512] + b[tid + 512]);
}

// ---------------- LN2 + gate logits + top-2 routing ----------------
__global__ __launch_bounds__(256)
void ln2_gate(const float* __restrict__ x1, const float* __restrict__ w, const float* __restrict__ b,
              const float* __restrict__ gate_w, u16* __restrict__ h2,
              float* __restrict__ logits, float* __restrict__ selw, int* __restrict__ seli)
{
  const int t = blockIdx.x, tid = threadIdx.x;
  const float* xr = x1 + (size_t)t * DMODEL;
  const float v0 = xr[tid], v1 = xr[tid + 256], v2 = xr[tid + 512];
  float s = v0 + v1 + v2, ss = v0 * v0 + v1 * v1 + v2 * v2;
  #pragma unroll
  for (int d = 1; d < 64; d <<= 1) { s += __shfl_xor(s, d); ss += __shfl_xor(ss, d); }
  __shared__ float rs[4], rq[4];
  if ((tid & 63) == 0) { rs[tid >> 6] = s; rq[tid >> 6] = ss; }
  __syncthreads();
  s  = rs[0] + rs[1] + rs[2] + rs[3];
  ss = rq[0] + rq[1] + rq[2] + rq[3];
  const float mean = s * (1.f / DMODEL);
  const float rstd = rsqrtf(ss * (1.f / DMODEL) - mean * mean + 1e-5f);
  __shared__ float row[DMODEL];
  const float y0 = (v0 - mean) * rstd * w[tid]       + b[tid];
  const float y1 = (v1 - mean) * rstd * w[tid + 256] + b[tid + 256];
  const float y2 = (v2 - mean) * rstd * w[tid + 512] + b[tid + 512];
  row[tid] = y0; row[tid + 256] = y1; row[tid + 512] = y2;
  u16* hr = h2 + (size_t)t * DMODEL;
  hr[tid] = f2bf(y0); hr[tid + 256] = f2bf(y1); hr[tid + 512] = f2bf(y2);
  __syncthreads();
  __shared__ float lg[NEXP];
  if (tid < 64) {
    const int e = tid >> 3, j = tid & 7;
    const float* gw = gate_w + e * DMODEL;
    float a = 0.f;
    for (int d = j; d < DMODEL; d += 8) a += row[d] * gw[d];
    a += __shfl_xor(a, 1); a += __shfl_xor(a, 2); a += __shfl_xor(a, 4);
    if (j == 0) lg[e] = a;
  }
  __syncthreads();
  if (tid < NEXP) logits[(size_t)t * NEXP + tid] = lg[tid];
  if (tid == 0) {
    int ia = 0, ib = -1;
    float va = -1e30f, vb = -1e30f;
    #pragma unroll
    for (int e = 0; e < NEXP; e++) {
      const float p = lg[e];
      if (p > va)      { vb = va; ib = ia; va = p; ia = e; }
      else if (p > vb) { vb = p; ib = e; }
    }
    const float pb = __expf(vb - va);          // softmax of {va,vb}; full-Z cancels in renorm
    const float inv = 1.f / (1.f + pb);
    selw[2 * t]     = inv;
    selw[2 * t + 1] = pb * inv;
    seli[2 * t]     = ia;
    seli[2 * t + 1] = ib;
  }
}

// ---------------- deterministic token->expert compaction ----------------
__global__ __launch_bounds__(256)
void route_count(const int* __restrict__ seli, int* __restrict__ blkcnt)
{
  __shared__ int c[NEXP];
  const int tid = threadIdx.x;
  if (tid < NEXP) c[tid] = 0;
  __syncthreads();
  const int t = blockIdx.x * 256 + tid;
  atomicAdd(&c[seli[2 * t]], 1);
  atomicAdd(&c[seli[2 * t + 1]], 1);
  __syncthreads();
  if (tid < NEXP) blkcnt[blockIdx.x * NEXP + tid] = c[tid];
}

// also builds the live-tile work list (128-row tiles): wl[i] = (e<<16)|bm_local, nwork[0] = count
__global__ void route_scan(const int* __restrict__ blkcnt, int* __restrict__ offs,
                           int* __restrict__ blkbase, int* __restrict__ wl, int* __restrict__ nwork)
{
  const int tid = threadIdx.x;   // 64 threads
  __shared__ int tot[NEXP];
  __shared__ int off_s[NEXP + 1];
  if (tid < NEXP) {
    int s = 0;
    for (int blk = 0; blk < 32; blk++) s += blkcnt[blk * NEXP + tid];
    tot[tid] = s;
  }
  __syncthreads();
  if (tid == 0) {
    int run = 0;
    for (int e = 0; e < NEXP; e++) { off_s[e] = run; run += tot[e]; }
    off_s[NEXP] = run;
    int nw = 0;
    for (int e = 0; e < NEXP; e++) {
      const int nb = (tot[e] + 127) >> 7;
      for (int i2 = 0; i2 < nb; i2++) wl[nw++] = (e << 16) | i2;
    }
    nwork[0] = nw;
  }
  __syncthreads();
  if (tid <= NEXP) offs[tid] = off_s[tid];
  if (tid < NEXP) {
    int run = off_s[tid];
    for (int blk = 0; blk < 32; blk++) { blkbase[blk * NEXP + tid] = run; run += blkcnt[blk * NEXP + tid]; }
  }
}

__global__ __launch_bounds__(256)
void route_place(const int* __restrict__ seli, const int* __restrict__ blkbase,
                 int* __restrict__ perm, int* __restrict__ posmap)
{
  __shared__ int cnts[2][4][NEXP];
  __shared__ int base[NEXP];
  const int tid = threadIdx.x, l = tid & 63, w = tid >> 6, blk = blockIdx.x;
  const int t = blk * 256 + tid;
  const unsigned long long ltm = (1ull << l) - 1ull;
  int my_e[2], my_r[2];
  my_e[0] = seli[2 * t]; my_e[1] = seli[2 * t + 1];
  my_r[0] = 0; my_r[1] = 0;
  if (tid < NEXP) base[tid] = blkbase[blk * NEXP + tid];
  #pragma unroll
  for (int k = 0; k < 2; k++) {
    #pragma unroll
    for (int ee = 0; ee < NEXP; ee++) {
      const unsigned long long msk = __ballot(my_e[k] == ee);
      if (my_e[k] == ee) my_r[k] = (int)__popcll(msk & ltm);
      if (l == ee) cnts[k][w][ee] = (int)__popcll(msk);
    }
  }
  __syncthreads();
  #pragma unroll
  for (int k = 0; k < 2; k++) {
    const int e = my_e[k];
    int pre = base[e];
    for (int k2 = 0; k2 < 2; k2++)
      for (int w2 = 0; w2 < 4; w2++)
        if (k2 < k || (k2 == k && w2 < w)) pre += cnts[k2][w2][e];
    const int pos = pre + my_r[k];
    perm[pos] = t;
    posmap[2 * t + k] = pos;
  }
}

// ------- 128x128x64 bf16 MFMA GEMM: 2-phase dbuf, counted vmcnt (R7 structure) -------
// BM-MAJOR work enumeration + XCD chunking (T1 revised): consecutive blocks in an XCD
// chunk share the A-tile (196 KB -> L2-hit after first touch; kills the 18-24x A re-read
// that dominated FETCH_SIZE), and successive bm within an expert reuse its B panels.
// Swapped MFMA operands -> vectorized epilogue. LDS swizzled (rule #21 both-sides).
template<int MODE>  // 0=QKV(bf16,+bias) 1=outproj(f32,+bias,+resid) 2=FFN1(gelu,bf16) 3=FFN2(bf16)
__global__ __launch_bounds__(256)
void gemm128(const u16* __restrict__ A, const u16* __restrict__ Bw,
             int M, int N, int Kd,
             const float* __restrict__ bias, const float* __restrict__ resid,
             void* __restrict__ outp,
             const int* __restrict__ perm, const int* __restrict__ offs,
             const int* __restrict__ wl, const int* __restrict__ nwork)
{
  __shared__ u16 As[2][128 * 64];
  __shared__ u16 Bs[2][128 * 64];
  const int tid = threadIdx.x;
  const int l   = tid & 63;
  const int w   = tid >> 6;
  const int wm  = w >> 1, wn = w & 1;

  const int nbn = N >> 7;
  int gbase = 0, cnt = M, e = 0, bm, bn;
  if (MODE >= 2) {
    const int nw  = nwork[0];
    const int nwg = nw * nbn;
    if ((int)blockIdx.x >= nwg) return;       // compact work list; cheap uniform exit
    const int t = xcd_swz(blockIdx.x, nwg);   // bm-major: t = bmi*nbn + bn
    const int bmi = t / nbn;
    bn = t - bmi * nbn;
    const int wk = wl[bmi];
    e  = wk >> 16;
    bm = wk & 0xffff;
    gbase = offs[e];
    cnt   = offs[e + 1] - gbase;
  } else {
    const int t = xcd_swz(blockIdx.x, gridDim.x);  // bm-major
    bm = t / nbn;
    bn = t - bm * nbn;
  }
  const u16*   Bp = Bw   + (MODE >= 2 ? (size_t)e * N * Kd : 0);
  const float* bp = bias + (MODE >= 2 ? e * N : 0);

  int arow[4], acol[4], brow[4];
  #pragma unroll
  for (int i = 0; i < 4; i++) {
    const int c = tid + 256 * i;
    const int r = c >> 3;
    const int f = (r & 7) ^ ((r >> 3) & 7);
    acol[i] = ((c & 7) ^ f) * 8;          // pre-swizzled source column (16B chunk)
    brow[i] = bn * 128 + r;
    int g;
    if (MODE == 2)      { int gp = gbase + bm * 128 + r; if (gp > NGATH - 1) gp = NGATH - 1; g = perm[gp]; }
    else if (MODE == 3) { int gp = gbase + bm * 128 + r; if (gp > NGATH - 1) gp = NGATH - 1; g = gp; }
    else                g = bm * 128 + r;
    arow[i] = g;
  }

  f32x4 acc[4][4] = {};
  const int nk = Kd >> 6;

  // prologue: stage tile 0 into buffer 0
  #pragma unroll
  for (int i = 0; i < 4; i++) {
    gl_lds16(A  + (size_t)arow[i] * Kd + acol[i], &As[0][(i * 256 + w * 64) * 8]);
    gl_lds16(Bp + (size_t)brow[i] * Kd + acol[i], &Bs[0][(i * 256 + w * 64) * 8]);
  }

  int cur = 0;
  for (int kt = 0; kt < nk; kt++) {
    const bool pf = (kt + 1 < nk);
    if (pf) {
      const int kb = (kt + 1) * 64;
      #pragma unroll
      for (int i = 0; i < 4; i++) {
        gl_lds16(A  + (size_t)arow[i] * Kd + kb + acol[i], &As[cur ^ 1][(i * 256 + w * 64) * 8]);
        gl_lds16(Bp + (size_t)brow[i] * Kd + kb + acol[i], &Bs[cur ^ 1][(i * 256 + w * 64) * 8]);
      }
      asm volatile("s_waitcnt vmcnt(8)" ::: "memory");   // drain tile kt; leave kt+1 in flight
    } else {
      asm volatile("s_waitcnt vmcnt(0)" ::: "memory");   // last tile: drain all
    }
    __builtin_amdgcn_s_barrier();                        // all waves' stage(kt) complete
    __builtin_amdgcn_sched_barrier(0);                   // no ds_read hoists above (rule 18)

    #pragma unroll
    for (int ks = 0; ks < 2; ks++) {
      bf16x8 af[4], bv[4];
      #pragma unroll
      for (int m = 0; m < 4; m++) {
        const int row = wm * 64 + m * 16 + (l & 15);
        af[m] = *(const bf16x8*)((const char*)&As[cur][0] +
                  ((row * 128 + ks * 64 + (l >> 4) * 16) ^ swz64(row)));
      }
      #pragma unroll
      for (int n = 0; n < 4; n++) {
        const int row = wn * 64 + n * 16 + (l & 15);
        bv[n] = *(const bf16x8*)((const char*)&Bs[cur][0] +
                  ((row * 128 + ks * 64 + (l >> 4) * 16) ^ swz64(row)));
      }
      #pragma unroll
      for (int m = 0; m < 4; m++)
        #pragma unroll
        for (int n = 0; n < 4; n++)
          acc[m][n] = __builtin_amdgcn_mfma_f32_16x16x32_bf16(bv[n], af[m], acc[m][n], 0, 0, 0);
    }
    if (pf) __builtin_amdgcn_s_barrier();   // compute done before next stage overwrites buf
    cur ^= 1;
  }

  // epilogue: lane holds out(row = bm*128 + wm*64 + m*16 + (l&15), cols c0[n]..c0[n]+3)
  f32x4 biasv[4];
  int   c0[4];
  #pragma unroll
  for (int n = 0; n < 4; n++) {
    c0[n] = bn * 128 + wn * 64 + n * 16 + ((l >> 4) << 2);
    biasv[n] = *(const f32x4*)(bp + c0[n]);
  }
  #pragma unroll
  for (int m = 0; m < 4; m++) {
    const int row = bm * 128 + wm * 64 + m * 16 + (l & 15);   // local for MODE>=2
    #pragma unroll
    for (int n = 0; n < 4; n++) {
      f32x4 v = acc[m][n] + biasv[n];
      if (MODE == 0) {
        *(uint2*)((u16*)outp + (size_t)row * N + c0[n]) =
            make_uint2(pkbf(v[0], v[1]), pkbf(v[2], v[3]));
      } else if (MODE == 1) {
        const size_t o = (size_t)row * N + c0[n];
        f32x4 rv = *(const f32x4*)(resid + o);
        v += rv;
        *(f32x4*)((float*)outp + o) = v;
      } else if (MODE == 2) {
        if (row < cnt) {
          #pragma unroll
          for (int r = 0; r < 4; r++)
            v[r] = v[r] * __builtin_amdgcn_rcpf(1.f + __expf(-1.702f * v[r]));  // QuickGELU
          *(uint2*)((u16*)outp + (size_t)(gbase + row) * FFDIM + c0[n]) =
              make_uint2(pkbf(v[0], v[1]), pkbf(v[2], v[3]));
        }
      } else {
        if (row < cnt)
          *(uint2*)((u16*)outp + (size_t)(gbase + row) * DMODEL + c0[n]) =
              make_uint2(pkbf(v[0], v[1]), pkbf(v[2], v[3]));
      }
    }
  }
}

// ---------------- flash attention: 1-D grid + XCD swizzle (KV locality), 4 waves ----------------
__global__ __launch_bounds__(256)
void attn_fwd(const u16* __restrict__ qkv, u16* __restrict__ o)
{
  __shared__ u16 Ksw[64 * 64];        // K tile [key][hd], swizzled
  __shared__ u16 Vt [64 * 64];        // V^T tile [hd][key], swizzled
  __shared__ u16 Pl [4 * 16 * 64];    // per-wave P tile [16 q][64 key], swizzled
  const int tid = threadIdx.x;
  const int l   = tid & 63, w = tid >> 6;
  // bh-major enumeration: blocks sharing (b,h) [= shared 256KB KV] land on the same XCD
  const int tt  = xcd_swz(blockIdx.x, 16 * BATCH * NHEAD);
  const int qt  = tt & 15;
  const int bh  = tt >> 4;
  const int b_  = bh / NHEAD;
  const int hh  = bh % NHEAD;

  // Q A-fragments (resident whole kernel)
  const int qrow = qt * 64 + w * 16 + (l & 15);
  const size_t qoff = ((size_t)(qrow * BATCH + b_)) * D3 + hh * HDIM + (l >> 4) * 8;
  const bf16x8 qa0 = *(const bf16x8*)&qkv[qoff];
  const bf16x8 qa1 = *(const bf16x8*)&qkv[qoff + 32];

  f32x4 oacc[4] = {};
  float m_[4], l_[4];
  #pragma unroll
  for (int r = 0; r < 4; r++) { m_[r] = -1e30f; l_[r] = 0.f; }

  u16* Pw = Pl + w * 1024;
  const int pswz = swz64(l & 15);

  for (int kt = 0; kt < 16; kt++) {
    // ---- stage K (linear rows, swizzled) and V (transposed scatter, swizzled) ----
    #pragma unroll
    for (int i = 0; i < 2; i++) {
      const int c = tid + 256 * i;
      const int key = c >> 3, dimb = (c & 7) * 8;
      const size_t gb = ((size_t)((kt * 64 + key) * BATCH + b_)) * D3 + hh * HDIM + dimb;
      const bf16x8 kd = *(const bf16x8*)&qkv[gb + DMODEL];
      const bf16x8 vd = *(const bf16x8*)&qkv[gb + 2 * DMODEL];
      *(bf16x8*)((char*)Ksw + ((key * 128 + dimb * 2) ^ swz64(key))) = kd;
      #pragma unroll
      for (int j = 0; j < 8; j++) {
        const int dim = dimb + j;
        *(u16*)((char*)Vt + ((dim * 128 + key * 2) ^ swz64(dim))) = (u16)vd[j];
      }
    }
    __syncthreads();

    // ---- S = Q K^T ----
    f32x4 sc[4] = {};
    #pragma unroll
    for (int kb2 = 0; kb2 < 4; kb2++) {
      const int key = kb2 * 16 + (l & 15);
      const int ksz = swz64(key);
      #pragma unroll
      for (int ks = 0; ks < 2; ks++) {
        const bf16x8 kf = *(const bf16x8*)((char*)Ksw +
            ((key * 128 + (ks * 32 + (l >> 4) * 8) * 2) ^ ksz));
        sc[kb2] = __builtin_amdgcn_mfma_f32_16x16x32_bf16(ks ? qa1 : qa0, kf, sc[kb2], 0, 0, 0);
      }
    }
    #pragma unroll
    for (int kb2 = 0; kb2 < 4; kb2++)
      #pragma unroll
      for (int r = 0; r < 4; r++) sc[kb2][r] *= 0.125f;   // hd^-0.5

    // ---- online softmax (rows live in 16-lane groups) ----
    float nm[4], corr[4], ps[4];
    #pragma unroll
    for (int r = 0; r < 4; r++) {
      float pm = fmaxf(fmaxf(sc[0][r], sc[1][r]), fmaxf(sc[2][r], sc[3][r]));
      pm = fmaxf(pm, __shfl_xor(pm, 1));
      pm = fmaxf(pm, __shfl_xor(pm, 2));
      pm = fmaxf(pm, __shfl_xor(pm, 4));
      pm = fmaxf(pm, __shfl_xor(pm, 8));
      nm[r]   = fmaxf(m_[r], pm);
      corr[r] = __expf(m_[r] - nm[r]);
      m_[r]   = nm[r];
      ps[r]   = 0.f;
    }
    #pragma unroll
    for (int kb2 = 0; kb2 < 4; kb2++) {
      #pragma unroll
      for (int r = 0; r < 4; r++) {
        const float p = __expf(sc[kb2][r] - nm[r]);
        ps[r] += p;
        const int prow = (l >> 4) * 4 + r;
        const int pcol = kb2 * 16 + (l & 15);
        *(u16*)((char*)Pw + ((prow * 128 + pcol * 2) ^ swz64(prow))) = f2bf(p);
      }
    }
    #pragma unroll
    for (int r = 0; r < 4; r++) {
      float s = ps[r];
      s += __shfl_xor(s, 1); s += __shfl_xor(s, 2);
      s += __shfl_xor(s, 4); s += __shfl_xor(s, 8);
      l_[r] = l_[r] * corr[r] + s;
      #pragma unroll
      for (int ob = 0; ob < 4; ob++) oacc[ob][r] *= corr[r];
    }

    // ---- O += P V  (P read back as A-frags; same-wave LDS is in-order) ----
    #pragma unroll
    for (int ob = 0; ob < 4; ob++) {
      const int dim = ob * 16 + (l & 15);
      const int vsz = swz64(dim);
      #pragma unroll
      for (int ks = 0; ks < 2; ks++) {
        const int kko = (ks * 32 + (l >> 4) * 8) * 2;
        const bf16x8 pf = *(const bf16x8*)((char*)Pw + (((l & 15) * 128 + kko) ^ pswz));
        const bf16x8 vf = *(const bf16x8*)((char*)Vt + ((dim * 128 + kko) ^ vsz));
        oacc[ob] = __builtin_amdgcn_mfma_f32_16x16x32_bf16(pf, vf, oacc[ob], 0, 0, 0);
      }
    }
    __syncthreads();
  }

  #pragma unroll
  for (int r = 0; r < 4; r++) {
    const float inv = 1.f / l_[r];
    const int qs = qt * 64 + w * 16 + (l >> 4) * 4 + r;
    #pragma unroll
    for (int ob = 0; ob < 4; ob++)
      o[((size_t)(qs * BATCH + b_)) * DMODEL + hh * HDIM + ob * 16 + (l & 15)] =
          f2bf(oacc[ob][r] * inv);
  }
}

// ---------------- final combine: out = x1 + w0*eout[p0] + w1*eout[p1] ----------------
__global__ __launch_bounds__(192)
void moe_combine(const float* __restrict__ x1, const u16* __restrict__ eout,
                 const int* __restrict__ posmap, const float* __restrict__ selw,
                 float* __restrict__ out)
{
  const int t = blockIdx.x, j = threadIdx.x;   // 192 threads * 4 = 768
  const int p0 = posmap[2 * t], p1 = posmap[2 * t + 1];
  const float w0 = selw[2 * t], w1 = selw[2 * t + 1];
  const float4 xv = ((const float4*)(x1 + (size_t)t * DMODEL))[j];
  const s16x4 a = ((const s16x4*)(eout + (size_t)p0 * DMODEL))[j];
  const s16x4 c = ((const s16x4*)(eout + (size_t)p1 * DMODEL))[j];
  float4 r;
  r.x = xv.x + w0 * bf2f((u16)a[0]) + w1 * bf2f((u16)c[0]);
  r.y = xv.y + w0 * bf2f((u16)a[1]) + w1 * bf2f((u16)c[1]);
  r.z = xv.z + w0 * bf2f((u16)a[2]) + w1 * bf2f((u16)c[2]);
  r.w = xv.w + w0 * bf2f((u16)a[3]) + w1 * bf2f((u16)c[3]);
  ((float4*)(out + (size_t)t * DMODEL))[j] = r;
}

// ---------------- workspace layout (needs ws_size >= ~255 MB) ----------------
#define MB (1ull << 20)
static const size_t OFF_H    = 0;                 // 12.6M  h bf16   (dead after QKV gemm)
static const size_t OFF_QKV  = 16 * MB;           // 37.75M          (dead after attention)
static const size_t OFF_O    = 54 * MB;           // 12.6M           (dead after out-proj)
static const size_t OFF_IPW  = 67 * MB;           // 3.54M           (dead after QKV gemm)
static const size_t OFF_OPW  = 71 * MB;           // 1.18M           (dead after out-proj)
static const size_t OFF_MID  = 0;                 // 100.7M mid bf16 (aliases all of the above)
static const size_t OFF_X1   = 101 * MB;          // 25.2M  x1 f32
static const size_t OFF_H2   = 127 * MB;          // 12.6M  h2 bf16
static const size_t OFF_W1T  = 140 * MB;          // 37.75M w1^T bf16
static const size_t OFF_W2T  = 178 * MB;          // 37.75M w2^T bf16
static const size_t OFF_EOUT = 216 * MB;          // 25.2M  expert out bf16
static const size_t OFF_SELW = 242 * MB;                    // T*2 f32
static const size_t OFF_PERM = 242 * MB + (1 << 16);        // NGATH i32
static const size_t OFF_POS  = 242 * MB + (2 << 16);        // T*2 i32
static const size_t OFF_SELI = 242 * MB + (3 << 16);        // T*2 i32
static const size_t OFF_BCNT = 242 * MB + (4 << 16);        // 32*8 i32
static const size_t OFF_BBASE= 242 * MB + (4 << 16) + 4096; // 32*8 i32
static const size_t OFF_OFFS = 242 * MB + (4 << 16) + 8192; // 9 i32
static const size_t OFF_WL   = 242 * MB + (5 << 16);        // work list i32
static const size_t OFF_NW   = 242 * MB + (5 << 16) + 1024; // 1 i32

extern "C" void kernel_launch(void* const* d_in, const int* in_sizes, int n_in,
                              void* d_out, int out_size, void* d_ws, size_t ws_size,
                              hipStream_t stream)
{
  const float* x     = (const float*)d_in[0];
  const float* ln1w  = (const float*)d_in[1];
  const float* ln1b  = (const float*)d_in[2];
  const float* ipw_f = (const float*)d_in[3];
  const float* ipb   = (const float*)d_in[4];
  const float* opw_f = (const float*)d_in[5];
  const float* opb   = (const float*)d_in[6];
  const float* ln2w  = (const float*)d_in[7];
  const float* ln2b  = (const float*)d_in[8];
  const float* gatew = (const float*)d_in[9];
  const float* w1    = (const float*)d_in[10];
  const float* b1    = (const float*)d_in[11];
  const float* w2    = (const float*)d_in[12];
  const float* b2    = (const float*)d_in[13];

  char* ws = (char*)d_ws;
  u16*   h    = (u16*)(ws + OFF_H);
  u16*   qkv  = (u16*)(ws + OFF_QKV);
  u16*   ob   = (u16*)(ws + OFF_O);
  u16*   ipw  = (u16*)(ws + OFF_IPW);
  u16*   opw  = (u16*)(ws + OFF_OPW);
  u16*   mid  = (u16*)(ws + OFF_MID);
  float* x1   = (float*)(ws + OFF_X1);
  u16*   h2   = (u16*)(ws + OFF_H2);
  u16*   w1t  = (u16*)(ws + OFF_W1T);
  u16*   w2t  = (u16*)(ws + OFF_W2T);
  u16*   eout = (u16*)(ws + OFF_EOUT);
  float* selw = (float*)(ws + OFF_SELW);
  int*   perm = (int*)(ws + OFF_PERM);
  int*   posm = (int*)(ws + OFF_POS);
  int*   seli = (int*)(ws + OFF_SELI);
  int*   bcnt = (int*)(ws + OFF_BCNT);
  int*   bbas = (int*)(ws + OFF_BBASE);
  int*   offs = (int*)(ws + OFF_OFFS);
  int*   wl   = (int*)(ws + OFF_WL);
  int*   nwork= (int*)(ws + OFF_NW);
  float* outx  = (float*)d_out;
  float* outlg = outx + (size_t)NTOK * DMODEL;

  // 1. weight conversions (must redo every call: deterministic, no caching)
  cvt_bf16<<<(D3 * DMODEL) / 1024, 256, 0, stream>>>(ipw_f, ipw, D3 * DMODEL);
  cvt_bf16<<<(DMODEL * DMODEL) / 1024, 256, 0, stream>>>(opw_f, opw, DMODEL * DMODEL);
  transpose_cvt<<<dim3(FFDIM / 64, DMODEL / 64, NEXP), 256, 0, stream>>>(w1, w1t, DMODEL, FFDIM);
  transpose_cvt<<<dim3(DMODEL / 64, FFDIM / 64, NEXP), 256, 0, stream>>>(w2, w2t, FFDIM, DMODEL);

  // 2. attention path
  ln_fwd<<<NTOK, 256, 0, stream>>>(x, ln1w, ln1b, h);
  gemm128<0><<<(NTOK / 128) * (D3 / 128), 256, 0, stream>>>(
      h, ipw, NTOK, D3, DMODEL, ipb, nullptr, qkv, nullptr, nullptr, nullptr, nullptr);
  attn_fwd<<<(S_LEN / 64) * BATCH * NHEAD, 256, 0, stream>>>(qkv, ob);
  gemm128<1><<<(NTOK / 128) * (DMODEL / 128), 256, 0, stream>>>(
      ob, opw, NTOK, DMODEL, DMODEL, opb, x, x1, nullptr, nullptr, nullptr, nullptr);

  // 3. routing
  ln2_gate<<<NTOK, 256, 0, stream>>>(x1, ln2w, ln2b, gatew, h2, outlg, selw, seli);
  route_count<<<32, 256, 0, stream>>>(seli, bcnt);
  route_scan<<<1, 64, 0, stream>>>(bcnt, offs, bbas, wl, nwork);
  route_place<<<32, 256, 0, stream>>>(seli, bbas, perm, posm);

  // 4. expert FFNs on compacted work list (live 128-row tiles only)
  gemm128<2><<<MAXWL * (FFDIM / 128), 256, 0, stream>>>(
      h2, w1t, NGATH, FFDIM, DMODEL, b1, nullptr, mid, perm, offs, wl, nwork);
  gemm128<3><<<MAXWL * (DMODEL / 128), 256, 0, stream>>>(
      mid, w2t, NGATH, DMODEL, FFDIM, b2, nullptr, eout, nullptr, offs, wl, nwork);

  // 5. combine + residual
  moe_combine<<<NTOK, 192, 0, stream>>>(x1, eout, posm, selw, outx);
}

// Round 13
// 515.199 us; speedup vs baseline: 1.0874x; 1.0202x over previous
//
#include <hip/hip_runtime.h>
#include <stdint.h>

#define S_LEN  1024
#define BATCH  8
#define DMODEL 768
#define NHEAD  12
#define HDIM   64
#define NEXP   8
#define FFDIM  3072
#define NTOK   8192     // S*B
#define D3     2304     // 3*D
#define NGATH  16384    // NTOK * topk(2)
#define MAXWL  136      // max live 128-row tiles across experts

typedef unsigned short u16;
typedef unsigned int   u32;
typedef __attribute__((ext_vector_type(8))) short bf16x8;
typedef __attribute__((ext_vector_type(4))) float f32x4;
typedef __attribute__((ext_vector_type(4))) short s16x4;

__device__ __forceinline__ u16 f2bf(float f){
  u32 x = __float_as_uint(f);
  x += 0x7fffu + ((x >> 16) & 1u);          // RNE
  return (u16)(x >> 16);
}
__device__ __forceinline__ float bf2f(u16 u){
  return __uint_as_float(((u32)u) << 16);
}
__device__ __forceinline__ u32 pkbf(float a, float b){   // lo=bf(a), hi=bf(b)
  u32 d; asm("v_cvt_pk_bf16_f32 %0, %1, %2" : "=v"(d) : "v"(a), "v"(b)); return d;
}
__device__ __forceinline__ void gl_lds16(const void* g, void* l){
  __builtin_amdgcn_global_load_lds(
      (const __attribute__((address_space(1))) u32*)(uintptr_t)g,
      (__attribute__((address_space(3))) u32*)(u32)(uintptr_t)l,
      16, 0, 0);
}
// XOR swizzle for 128B-stride row-major bf16 LDS tiles (G4 fix), 16B-chunk preserving
__device__ __forceinline__ int swz64(int r){ return ((r & 7) ^ ((r >> 3) & 7)) << 4; }

// bijective XCD-aware remap (m204): orig < nwg -> each XCD (orig%8) owns a contiguous
// chunk of the work enumeration. Perf-only heuristic (assumes dispatch XCD = orig%8).
__device__ __forceinline__ int xcd_swz(int orig, int nwg){
  const int q = nwg >> 3, r = nwg & 7;
  const int xcd = orig & 7, loc = orig >> 3;
  return (xcd < r ? xcd * (q + 1) : r * (q + 1) + (xcd - r) * q) + loc;
}

// ---------------- elementwise fp32 -> bf16 convert ----------------
__global__ __launch_bounds__(256)
void cvt_bf16(const float* __restrict__ in, u16* __restrict__ out, int n)
{
  int i = (blockIdx.x * 256 + threadIdx.x) * 4;
  if (i + 3 < n) {
    float4 v = *(const float4*)(in + i);
    out[i]     = f2bf(v.x);
    out[i + 1] = f2bf(v.y);
    out[i + 2] = f2bf(v.z);
    out[i + 3] = f2bf(v.w);
  }
}

// ------- transpose + convert v2: 64x64 tile, float4 loads, padded LDS, uint2 stores -------
// in[rows][cols] f32 -> out[cols][rows] bf16
__global__ __launch_bounds__(256)
void transpose_cvt(const float* __restrict__ in, u16* __restrict__ out, int rows, int cols)
{
  __shared__ float tile[64][65];
  const size_t eo = (size_t)blockIdx.z * rows * cols;
  in  += eo; out += eo;
  const int bx = blockIdx.x * 64;   // input col base
  const int by = blockIdx.y * 64;   // input row base
  const int tid = threadIdx.x;
  #pragma unroll
  for (int i = 0; i < 4; i++) {
    const int c = tid + 256 * i;            // 1024 float4 chunks
    const int r = c >> 4, c4 = (c & 15) * 4;
    const float4 v = *(const float4*)(in + (size_t)(by + r) * cols + bx + c4);
    tile[r][c4] = v.x; tile[r][c4 + 1] = v.y; tile[r][c4 + 2] = v.z; tile[r][c4 + 3] = v.w;
  }
  __syncthreads();
  #pragma unroll
  for (int i = 0; i < 4; i++) {
    const int c = tid + 256 * i;
    const int orow = c >> 4, r4 = (c & 15) * 4;   // orow = input col; r4 = input row base
    uint2 p;
    p.x = pkbf(tile[r4][orow],     tile[r4 + 1][orow]);
    p.y = pkbf(tile[r4 + 2][orow], tile[r4 + 3][orow]);
    *(uint2*)(out + (size_t)(bx + orow) * rows + by + r4) = p;
  }
}

// ---------------- LayerNorm (row = 768) -> bf16 ----------------
__global__ __launch_bounds__(256)
void ln_fwd(const float* __restrict__ x, const float* __restrict__ w, const float* __restrict__ b,
            u16* __restrict__ out)
{
  const int t = blockIdx.x, tid = threadIdx.x;
  const float* xr = x + (size_t)t * DMODEL;
  const float v0 = xr[tid], v1 = xr[tid + 256], v2 = xr[tid + 512];
  float s = v0 + v1 + v2, ss = v0 * v0 + v1 * v1 + v2 * v2;
  #pragma unroll
  for (int d = 1; d < 64; d <<= 1) { s += __shfl_xor(s, d); ss += __shfl_xor(ss, d); }
  __shared__ float rs[4], rq[4];
  if ((tid & 63) == 0) { rs[tid >> 6] = s; rq[tid >> 6] = ss; }
  __syncthreads();
  s  = rs[0] + rs[1] + rs[2] + rs[3];
  ss = rq[0] + rq[1] + rq[2] + rq[3];
  const float mean = s * (1.f / DMODEL);
  const float rstd = rsqrtf(ss * (1.f / DMODEL) - mean * mean + 1e-5f);
  u16* orow = out + (size_t)t * DMODEL;
  orow[tid]       = f2bf((v0 - mean) * rstd * w[tid]       + b[tid]);
  orow[tid + 256] = f2bf((v1 - mean) * rstd * w[tid + 256] + b[tid + 256]);
  orow[tid + 512] = f2bf((v2 - mean) * rstd * w[tid + 512] + b[tid + 512]);
}

// ---------------- LN2 + gate logits + top-2 routing ----------------
__global__ __launch_bounds__(256)
void ln2_gate(const float* __restrict__ x1, const float* __restrict__ w, const float* __restrict__ b,
              const float* __restrict__ gate_w, u16* __restrict__ h2,
              float* __restrict__ logits, float* __restrict__ selw, int* __restrict__ seli)
{
  const int t = blockIdx.x, tid = threadIdx.x;
  const float* xr = x1 + (size_t)t * DMODEL;
  const float v0 = xr[tid], v1 = xr[tid + 256], v2 = xr[tid + 512];
  float s = v0 + v1 + v2, ss = v0 * v0 + v1 * v1 + v2 * v2;
  #pragma unroll
  for (int d = 1; d < 64; d <<= 1) { s += __shfl_xor(s, d); ss += __shfl_xor(ss, d); }
  __shared__ float rs[4], rq[4];
  if ((tid & 63) == 0) { rs[tid >> 6] = s; rq[tid >> 6] = ss; }
  __syncthreads();
  s  = rs[0] + rs[1] + rs[2] + rs[3];
  ss = rq[0] + rq[1] + rq[2] + rq[3];
  const float mean = s * (1.f / DMODEL);
  const float rstd = rsqrtf(ss * (1.f / DMODEL) - mean * mean + 1e-5f);
  __shared__ float row[DMODEL];
  const float y0 = (v0 - mean) * rstd * w[tid]       + b[tid];
  const float y1 = (v1 - mean) * rstd * w[tid + 256] + b[tid + 256];
  const float y2 = (v2 - mean) * rstd * w[tid + 512] + b[tid + 512];
  row[tid] = y0; row[tid + 256] = y1; row[tid + 512] = y2;
  u16* hr = h2 + (size_t)t * DMODEL;
  hr[tid] = f2bf(y0); hr[tid + 256] = f2bf(y1); hr[tid + 512] = f2bf(y2);
  __syncthreads();
  __shared__ float lg[NEXP];
  if (tid < 64) {
    const int e = tid >> 3, j = tid & 7;
    const float* gw = gate_w + e * DMODEL;
    float a = 0.f;
    for (int d = j; d < DMODEL; d += 8) a += row[d] * gw[d];
    a += __shfl_xor(a, 1); a += __shfl_xor(a, 2); a += __shfl_xor(a, 4);
    if (j == 0) lg[e] = a;
  }
  __syncthreads();
  if (tid < NEXP) logits[(size_t)t * NEXP + tid] = lg[tid];
  if (tid == 0) {
    int ia = 0, ib = -1;
    float va = -1e30f, vb = -1e30f;
    #pragma unroll
    for (int e = 0; e < NEXP; e++) {
      const float p = lg[e];
      if (p > va)      { vb = va; ib = ia; va = p; ia = e; }
      else if (p > vb) { vb = p; ib = e; }
    }
    const float pb = __expf(vb - va);          // softmax of {va,vb}; full-Z cancels in renorm
    const float inv = 1.f / (1.f + pb);
    selw[2 * t]     = inv;
    selw[2 * t + 1] = pb * inv;
    seli[2 * t]     = ia;
    seli[2 * t + 1] = ib;
  }
}

// ---------------- deterministic token->expert compaction ----------------
__global__ __launch_bounds__(256)
void route_count(const int* __restrict__ seli, int* __restrict__ blkcnt)
{
  __shared__ int c[NEXP];
  const int tid = threadIdx.x;
  if (tid < NEXP) c[tid] = 0;
  __syncthreads();
  const int t = blockIdx.x * 256 + tid;
  atomicAdd(&c[seli[2 * t]], 1);
  atomicAdd(&c[seli[2 * t + 1]], 1);
  __syncthreads();
  if (tid < NEXP) blkcnt[blockIdx.x * NEXP + tid] = c[tid];
}

// also builds the live-tile work list (128-row tiles): wl[i] = (e<<16)|bm_local, nwork[0] = count
__global__ void route_scan(const int* __restrict__ blkcnt, int* __restrict__ offs,
                           int* __restrict__ blkbase, int* __restrict__ wl, int* __restrict__ nwork)
{
  const int tid = threadIdx.x;   // 64 threads
  __shared__ int tot[NEXP];
  __shared__ int off_s[NEXP + 1];
  if (tid < NEXP) {
    int s = 0;
    for (int blk = 0; blk < 32; blk++) s += blkcnt[blk * NEXP + tid];
    tot[tid] = s;
  }
  __syncthreads();
  if (tid == 0) {
    int run = 0;
    for (int e = 0; e < NEXP; e++) { off_s[e] = run; run += tot[e]; }
    off_s[NEXP] = run;
    int nw = 0;
    for (int e = 0; e < NEXP; e++) {
      const int nb = (tot[e] + 127) >> 7;
      for (int i2 = 0; i2 < nb; i2++) wl[nw++] = (e << 16) | i2;
    }
    nwork[0] = nw;
  }
  __syncthreads();
  if (tid <= NEXP) offs[tid] = off_s[tid];
  if (tid < NEXP) {
    int run = off_s[tid];
    for (int blk = 0; blk < 32; blk++) { blkbase[blk * NEXP + tid] = run; run += blkcnt[blk * NEXP + tid]; }
  }
}

__global__ __launch_bounds__(256)
void route_place(const int* __restrict__ seli, const int* __restrict__ blkbase,
                 int* __restrict__ perm, int* __restrict__ posmap)
{
  __shared__ int cnts[2][4][NEXP];
  __shared__ int base[NEXP];
  const int tid = threadIdx.x, l = tid & 63, w = tid >> 6, blk = blockIdx.x;
  const int t = blk * 256 + tid;
  const unsigned long long ltm = (1ull << l) - 1ull;
  int my_e[2], my_r[2];
  my_e[0] = seli[2 * t]; my_e[1] = seli[2 * t + 1];
  my_r[0] = 0; my_r[1] = 0;
  if (tid < NEXP) base[tid] = blkbase[blk * NEXP + tid];
  #pragma unroll
  for (int k = 0; k < 2; k++) {
    #pragma unroll
    for (int ee = 0; ee < NEXP; ee++) {
      const unsigned long long msk = __ballot(my_e[k] == ee);
      if (my_e[k] == ee) my_r[k] = (int)__popcll(msk & ltm);
      if (l == ee) cnts[k][w][ee] = (int)__popcll(msk);
    }
  }
  __syncthreads();
  #pragma unroll
  for (int k = 0; k < 2; k++) {
    const int e = my_e[k];
    int pre = base[e];
    for (int k2 = 0; k2 < 2; k2++)
      for (int w2 = 0; w2 < 4; w2++)
        if (k2 < k || (k2 == k && w2 < w)) pre += cnts[k2][w2][e];
    const int pos = pre + my_r[k];
    perm[pos] = t;
    posmap[2 * t + k] = pos;
  }
}

// ------- 128x128x64 bf16 MFMA GEMM: 2-phase dbuf, counted vmcnt (R7 structure) -------
// Work enumeration: bn-GROUP tiling x bm-major x XCD chunking. t = (g*nw + bmi)*GRP + bnin.
// XCD chunk resident set = one A-tile (196 KB) + GRP B-panels (<=2.4 MB) <= per-XCD L2,
// killing both the A re-read (R11 fix) and the B-panel thrash (R12 residual: expert
// panel 4.7 MB > 4 MB L2 evicted every bm sweep).
// Swapped MFMA operands -> vectorized epilogue. LDS swizzled (rule #21 both-sides).
template<int MODE, int GRP>  // 0=QKV 1=outproj(+resid,f32) 2=FFN1(gelu) 3=FFN2
__global__ __launch_bounds__(256)
void gemm128(const u16* __restrict__ A, const u16* __restrict__ Bw,
             int M, int N, int Kd,
             const float* __restrict__ bias, const float* __restrict__ resid,
             void* __restrict__ outp,
             const int* __restrict__ perm, const int* __restrict__ offs,
             const int* __restrict__ wl, const int* __restrict__ nwork)
{
  __shared__ u16 As[2][128 * 64];
  __shared__ u16 Bs[2][128 * 64];
  const int tid = threadIdx.x;
  const int l   = tid & 63;
  const int w   = tid >> 6;
  const int wm  = w >> 1, wn = w & 1;

  int gbase = 0, cnt = M, e = 0, bm, bn;
  if (MODE >= 2) {
    const int nw  = nwork[0];
    const int nwg = nw * (N >> 7);
    if ((int)blockIdx.x >= nwg) return;       // compact work list; cheap uniform exit
    const int t    = xcd_swz(blockIdx.x, nwg);
    const int bnin = t % GRP;                 // GRP compile-time -> cheap
    const int q    = t / GRP;
    const int bmi  = q % nw;                  // runtime div, once per block
    bn = (q / nw) * GRP + bnin;
    const int wk = wl[bmi];
    e  = wk >> 16;
    bm = wk & 0xffff;
    gbase = offs[e];
    cnt   = offs[e + 1] - gbase;
  } else {
    const int nwm = M >> 7;
    const int t    = xcd_swz(blockIdx.x, gridDim.x);
    const int bnin = t % GRP;
    const int q    = t / GRP;
    bm = q % nwm;
    bn = (q / nwm) * GRP + bnin;
  }
  const u16*   Bp = Bw   + (MODE >= 2 ? (size_t)e * N * Kd : 0);
  const float* bp = bias + (MODE >= 2 ? e * N : 0);

  int arow[4], acol[4], brow[4];
  #pragma unroll
  for (int i = 0; i < 4; i++) {
    const int c = tid + 256 * i;
    const int r = c >> 3;
    const int f = (r & 7) ^ ((r >> 3) & 7);
    acol[i] = ((c & 7) ^ f) * 8;          // pre-swizzled source column (16B chunk)
    brow[i] = bn * 128 + r;
    int g;
    if (MODE == 2)      { int gp = gbase + bm * 128 + r; if (gp > NGATH - 1) gp = NGATH - 1; g = perm[gp]; }
    else if (MODE == 3) { int gp = gbase + bm * 128 + r; if (gp > NGATH - 1) gp = NGATH - 1; g = gp; }
    else                g = bm * 128 + r;
    arow[i] = g;
  }

  f32x4 acc[4][4] = {};
  const int nk = Kd >> 6;

  // prologue: stage tile 0 into buffer 0
  #pragma unroll
  for (int i = 0; i < 4; i++) {
    gl_lds16(A  + (size_t)arow[i] * Kd + acol[i], &As[0][(i * 256 + w * 64) * 8]);
    gl_lds16(Bp + (size_t)brow[i] * Kd + acol[i], &Bs[0][(i * 256 + w * 64) * 8]);
  }

  int cur = 0;
  for (int kt = 0; kt < nk; kt++) {
    const bool pf = (kt + 1 < nk);
    if (pf) {
      const int kb = (kt + 1) * 64;
      #pragma unroll
      for (int i = 0; i < 4; i++) {
        gl_lds16(A  + (size_t)arow[i] * Kd + kb + acol[i], &As[cur ^ 1][(i * 256 + w * 64) * 8]);
        gl_lds16(Bp + (size_t)brow[i] * Kd + kb + acol[i], &Bs[cur ^ 1][(i * 256 + w * 64) * 8]);
      }
      asm volatile("s_waitcnt vmcnt(8)" ::: "memory");   // drain tile kt; leave kt+1 in flight
    } else {
      asm volatile("s_waitcnt vmcnt(0)" ::: "memory");   // last tile: drain all
    }
    __builtin_amdgcn_s_barrier();                        // all waves' stage(kt) complete
    __builtin_amdgcn_sched_barrier(0);                   // no ds_read hoists above (rule 18)

    #pragma unroll
    for (int ks = 0; ks < 2; ks++) {
      bf16x8 af[4], bv[4];
      #pragma unroll
      for (int m = 0; m < 4; m++) {
        const int row = wm * 64 + m * 16 + (l & 15);
        af[m] = *(const bf16x8*)((const char*)&As[cur][0] +
                  ((row * 128 + ks * 64 + (l >> 4) * 16) ^ swz64(row)));
      }
      #pragma unroll
      for (int n = 0; n < 4; n++) {
        const int row = wn * 64 + n * 16 + (l & 15);
        bv[n] = *(const bf16x8*)((const char*)&Bs[cur][0] +
                  ((row * 128 + ks * 64 + (l >> 4) * 16) ^ swz64(row)));
      }
      #pragma unroll
      for (int m = 0; m < 4; m++)
        #pragma unroll
        for (int n = 0; n < 4; n++)
          acc[m][n] = __builtin_amdgcn_mfma_f32_16x16x32_bf16(bv[n], af[m], acc[m][n], 0, 0, 0);
    }
    if (pf) __builtin_amdgcn_s_barrier();   // compute done before next stage overwrites buf
    cur ^= 1;
  }

  // epilogue: lane holds out(row = bm*128 + wm*64 + m*16 + (l&15), cols c0[n]..c0[n]+3)
  f32x4 biasv[4];
  int   c0[4];
  #pragma unroll
  for (int n = 0; n < 4; n++) {
    c0[n] = bn * 128 + wn * 64 + n * 16 + ((l >> 4) << 2);
    biasv[n] = *(const f32x4*)(bp + c0[n]);
  }
  #pragma unroll
  for (int m = 0; m < 4; m++) {
    const int row = bm * 128 + wm * 64 + m * 16 + (l & 15);   // local for MODE>=2
    #pragma unroll
    for (int n = 0; n < 4; n++) {
      f32x4 v = acc[m][n] + biasv[n];
      if (MODE == 0) {
        *(uint2*)((u16*)outp + (size_t)row * N + c0[n]) =
            make_uint2(pkbf(v[0], v[1]), pkbf(v[2], v[3]));
      } else if (MODE == 1) {
        const size_t o = (size_t)row * N + c0[n];
        f32x4 rv = *(const f32x4*)(resid + o);
        v += rv;
        *(f32x4*)((float*)outp + o) = v;
      } else if (MODE == 2) {
        if (row < cnt) {
          #pragma unroll
          for (int r = 0; r < 4; r++)
            v[r] = v[r] * __builtin_amdgcn_rcpf(1.f + __expf(-1.702f * v[r]));  // QuickGELU
          *(uint2*)((u16*)outp + (size_t)(gbase + row) * FFDIM + c0[n]) =
              make_uint2(pkbf(v[0], v[1]), pkbf(v[2], v[3]));
        }
      } else {
        if (row < cnt)
          *(uint2*)((u16*)outp + (size_t)(gbase + row) * DMODEL + c0[n]) =
              make_uint2(pkbf(v[0], v[1]), pkbf(v[2], v[3]));
      }
    }
  }
}

// ---------------- flash attention: 1-D grid + XCD swizzle (KV locality), 4 waves ----------------
__global__ __launch_bounds__(256)
void attn_fwd(const u16* __restrict__ qkv, u16* __restrict__ o)
{
  __shared__ u16 Ksw[64 * 64];        // K tile [key][hd], swizzled
  __shared__ u16 Vt [64 * 64];        // V^T tile [hd][key], swizzled
  __shared__ u16 Pl [4 * 16 * 64];    // per-wave P tile [16 q][64 key], swizzled
  const int tid = threadIdx.x;
  const int l   = tid & 63, w = tid >> 6;
  // bh-major enumeration: blocks sharing (b,h) [= shared 256KB KV] land on the same XCD
  const int tt  = xcd_swz(blockIdx.x, 16 * BATCH * NHEAD);
  const int qt  = tt & 15;
  const int bh  = tt >> 4;
  const int b_  = bh / NHEAD;
  const int hh  = bh % NHEAD;

  // Q A-fragments (resident whole kernel)
  const int qrow = qt * 64 + w * 16 + (l & 15);
  const size_t qoff = ((size_t)(qrow * BATCH + b_)) * D3 + hh * HDIM + (l >> 4) * 8;
  const bf16x8 qa0 = *(const bf16x8*)&qkv[qoff];
  const bf16x8 qa1 = *(const bf16x8*)&qkv[qoff + 32];

  f32x4 oacc[4] = {};
  float m_[4], l_[4];
  #pragma unroll
  for (int r = 0; r < 4; r++) { m_[r] = -1e30f; l_[r] = 0.f; }

  u16* Pw = Pl + w * 1024;
  const int pswz = swz64(l & 15);

  for (int kt = 0; kt < 16; kt++) {
    // ---- stage K (linear rows, swizzled) and V (transposed scatter, swizzled) ----
    #pragma unroll
    for (int i = 0; i < 2; i++) {
      const int c = tid + 256 * i;
      const int key = c >> 3, dimb = (c & 7) * 8;
      const size_t gb = ((size_t)((kt * 64 + key) * BATCH + b_)) * D3 + hh * HDIM + dimb;
      const bf16x8 kd = *(const bf16x8*)&qkv[gb + DMODEL];
      const bf16x8 vd = *(const bf16x8*)&qkv[gb + 2 * DMODEL];
      *(bf16x8*)((char*)Ksw + ((key * 128 + dimb * 2) ^ swz64(key))) = kd;
      #pragma unroll
      for (int j = 0; j < 8; j++) {
        const int dim = dimb + j;
        *(u16*)((char*)Vt + ((dim * 128 + key * 2) ^ swz64(dim))) = (u16)vd[j];
      }
    }
    __syncthreads();

    // ---- S = Q K^T ----
    f32x4 sc[4] = {};
    #pragma unroll
    for (int kb2 = 0; kb2 < 4; kb2++) {
      const int key = kb2 * 16 + (l & 15);
      const int ksz = swz64(key);
      #pragma unroll
      for (int ks = 0; ks < 2; ks++) {
        const bf16x8 kf = *(const bf16x8*)((char*)Ksw +
            ((key * 128 + (ks * 32 + (l >> 4) * 8) * 2) ^ ksz));
        sc[kb2] = __builtin_amdgcn_mfma_f32_16x16x32_bf16(ks ? qa1 : qa0, kf, sc[kb2], 0, 0, 0);
      }
    }
    #pragma unroll
    for (int kb2 = 0; kb2 < 4; kb2++)
      #pragma unroll
      for (int r = 0; r < 4; r++) sc[kb2][r] *= 0.125f;   // hd^-0.5

    // ---- online softmax (rows live in 16-lane groups) ----
    float nm[4], corr[4], ps[4];
    #pragma unroll
    for (int r = 0; r < 4; r++) {
      float pm = fmaxf(fmaxf(sc[0][r], sc[1][r]), fmaxf(sc[2][r], sc[3][r]));
      pm = fmaxf(pm, __shfl_xor(pm, 1));
      pm = fmaxf(pm, __shfl_xor(pm, 2));
      pm = fmaxf(pm, __shfl_xor(pm, 4));
      pm = fmaxf(pm, __shfl_xor(pm, 8));
      nm[r]   = fmaxf(m_[r], pm);
      corr[r] = __expf(m_[r] - nm[r]);
      m_[r]   = nm[r];
      ps[r]   = 0.f;
    }
    #pragma unroll
    for (int kb2 = 0; kb2 < 4; kb2++) {
      #pragma unroll
      for (int r = 0; r < 4; r++) {
        const float p = __expf(sc[kb2][r] - nm[r]);
        ps[r] += p;
        const int prow = (l >> 4) * 4 + r;
        const int pcol = kb2 * 16 + (l & 15);
        *(u16*)((char*)Pw + ((prow * 128 + pcol * 2) ^ swz64(prow))) = f2bf(p);
      }
    }
    #pragma unroll
    for (int r = 0; r < 4; r++) {
      float s = ps[r];
      s += __shfl_xor(s, 1); s += __shfl_xor(s, 2);
      s += __shfl_xor(s, 4); s += __shfl_xor(s, 8);
      l_[r] = l_[r] * corr[r] + s;
      #pragma unroll
      for (int ob = 0; ob < 4; ob++) oacc[ob][r] *= corr[r];
    }

    // ---- O += P V  (P read back as A-frags; same-wave LDS is in-order) ----
    #pragma unroll
    for (int ob = 0; ob < 4; ob++) {
      const int dim = ob * 16 + (l & 15);
      const int vsz = swz64(dim);
      #pragma unroll
      for (int ks = 0; ks < 2; ks++) {
        const int kko = (ks * 32 + (l >> 4) * 8) * 2;
        const bf16x8 pf = *(const bf16x8*)((char*)Pw + (((l & 15) * 128 + kko) ^ pswz));
        const bf16x8 vf = *(const bf16x8*)((char*)Vt + ((dim * 128 + kko) ^ vsz));
        oacc[ob] = __builtin_amdgcn_mfma_f32_16x16x32_bf16(pf, vf, oacc[ob], 0, 0, 0);
      }
    }
    __syncthreads();
  }

  #pragma unroll
  for (int r = 0; r < 4; r++) {
    const float inv = 1.f / l_[r];
    const int qs = qt * 64 + w * 16 + (l >> 4) * 4 + r;
    #pragma unroll
    for (int ob = 0; ob < 4; ob++)
      o[((size_t)(qs * BATCH + b_)) * DMODEL + hh * HDIM + ob * 16 + (l & 15)] =
          f2bf(oacc[ob][r] * inv);
  }
}

// ---------------- final combine: out = x1 + w0*eout[p0] + w1*eout[p1] ----------------
__global__ __launch_bounds__(192)
void moe_combine(const float* __restrict__ x1, const u16* __restrict__ eout,
                 const int* __restrict__ posmap, const float* __restrict__ selw,
                 float* __restrict__ out)
{
  const int t = blockIdx.x, j = threadIdx.x;   // 192 threads * 4 = 768
  const int p0 = posmap[2 * t], p1 = posmap[2 * t + 1];
  const float w0 = selw[2 * t], w1 = selw[2 * t + 1];
  const float4 xv = ((const float4*)(x1 + (size_t)t * DMODEL))[j];
  const s16x4 a = ((const s16x4*)(eout + (size_t)p0 * DMODEL))[j];
  const s16x4 c = ((const s16x4*)(eout + (size_t)p1 * DMODEL))[j];
  float4 r;
  r.x = xv.x + w0 * bf2f((u16)a[0]) + w1 * bf2f((u16)c[0]);
  r.y = xv.y + w0 * bf2f((u16)a[1]) + w1 * bf2f((u16)c[1]);
  r.z = xv.z + w0 * bf2f((u16)a[2]) + w1 * bf2f((u16)c[2]);
  r.w = xv.w + w0 * bf2f((u16)a[3]) + w1 * bf2f((u16)c[3]);
  ((float4*)(out + (size_t)t * DMODEL))[j] = r;
}

// ---------------- workspace layout (needs ws_size >= ~255 MB) ----------------
#define MB (1ull << 20)
static const size_t OFF_H    = 0;                 // 12.6M  h bf16   (dead after QKV gemm)
static const size_t OFF_QKV  = 16 * MB;           // 37.75M          (dead after attention)
static const size_t OFF_O    = 54 * MB;           // 12.6M           (dead after out-proj)
static const size_t OFF_IPW  = 67 * MB;           // 3.54M           (dead after QKV gemm)
static const size_t OFF_OPW  = 71 * MB;           // 1.18M           (dead after out-proj)
static const size_t OFF_MID  = 0;                 // 100.7M mid bf16 (aliases all of the above)
static const size_t OFF_X1   = 101 * MB;          // 25.2M  x1 f32
static const size_t OFF_H2   = 127 * MB;          // 12.6M  h2 bf16
static const size_t OFF_W1T  = 140 * MB;          // 37.75M w1^T bf16
static const size_t OFF_W2T  = 178 * MB;          // 37.75M w2^T bf16
static const size_t OFF_EOUT = 216 * MB;          // 25.2M  expert out bf16
static const size_t OFF_SELW = 242 * MB;                    // T*2 f32
static const size_t OFF_PERM = 242 * MB + (1 << 16);        // NGATH i32
static const size_t OFF_POS  = 242 * MB + (2 << 16);        // T*2 i32
static const size_t OFF_SELI = 242 * MB + (3 << 16);        // T*2 i32
static const size_t OFF_BCNT = 242 * MB + (4 << 16);        // 32*8 i32
static const size_t OFF_BBASE= 242 * MB + (4 << 16) + 4096; // 32*8 i32
static const size_t OFF_OFFS = 242 * MB + (4 << 16) + 8192; // 9 i32
static const size_t OFF_WL   = 242 * MB + (5 << 16);        // work list i32
static const size_t OFF_NW   = 242 * MB + (5 << 16) + 1024; // 1 i32

extern "C" void kernel_launch(void* const* d_in, const int* in_sizes, int n_in,
                              void* d_out, int out_size, void* d_ws, size_t ws_size,
                              hipStream_t stream)
{
  const float* x     = (const float*)d_in[0];
  const float* ln1w  = (const float*)d_in[1];
  const float* ln1b  = (const float*)d_in[2];
  const float* ipw_f = (const float*)d_in[3];
  const float* ipb   = (const float*)d_in[4];
  const float* opw_f = (const float*)d_in[5];
  const float* opb   = (const float*)d_in[6];
  const float* ln2w  = (const float*)d_in[7];
  const float* ln2b  = (const float*)d_in[8];
  const float* gatew = (const float*)d_in[9];
  const float* w1    = (const float*)d_in[10];
  const float* b1    = (const float*)d_in[11];
  const float* w2    = (const float*)d_in[12];
  const float* b2    = (const float*)d_in[13];

  char* ws = (char*)d_ws;
  u16*   h    = (u16*)(ws + OFF_H);
  u16*   qkv  = (u16*)(ws + OFF_QKV);
  u16*   ob   = (u16*)(ws + OFF_O);
  u16*   ipw  = (u16*)(ws + OFF_IPW);
  u16*   opw  = (u16*)(ws + OFF_OPW);
  u16*   mid  = (u16*)(ws + OFF_MID);
  float* x1   = (float*)(ws + OFF_X1);
  u16*   h2   = (u16*)(ws + OFF_H2);
  u16*   w1t  = (u16*)(ws + OFF_W1T);
  u16*   w2t  = (u16*)(ws + OFF_W2T);
  u16*   eout = (u16*)(ws + OFF_EOUT);
  float* selw = (float*)(ws + OFF_SELW);
  int*   perm = (int*)(ws + OFF_PERM);
  int*   posm = (int*)(ws + OFF_POS);
  int*   seli = (int*)(ws + OFF_SELI);
  int*   bcnt = (int*)(ws + OFF_BCNT);
  int*   bbas = (int*)(ws + OFF_BBASE);
  int*   offs = (int*)(ws + OFF_OFFS);
  int*   wl   = (int*)(ws + OFF_WL);
  int*   nwork= (int*)(ws + OFF_NW);
  float* outx  = (float*)d_out;
  float* outlg = outx + (size_t)NTOK * DMODEL;

  // 1. weight conversions (must redo every call: deterministic, no caching)
  cvt_bf16<<<(D3 * DMODEL) / 1024, 256, 0, stream>>>(ipw_f, ipw, D3 * DMODEL);
  cvt_bf16<<<(DMODEL * DMODEL) / 1024, 256, 0, stream>>>(opw_f, opw, DMODEL * DMODEL);
  transpose_cvt<<<dim3(FFDIM / 64, DMODEL / 64, NEXP), 256, 0, stream>>>(w1, w1t, DMODEL, FFDIM);
  transpose_cvt<<<dim3(DMODEL / 64, FFDIM / 64, NEXP), 256, 0, stream>>>(w2, w2t, FFDIM, DMODEL);

  // 2. attention path
  ln_fwd<<<NTOK, 256, 0, stream>>>(x, ln1w, ln1b, h);
  gemm128<0, 6><<<(NTOK / 128) * (D3 / 128), 256, 0, stream>>>(
      h, ipw, NTOK, D3, DMODEL, ipb, nullptr, qkv, nullptr, nullptr, nullptr, nullptr);
  attn_fwd<<<(S_LEN / 64) * BATCH * NHEAD, 256, 0, stream>>>(qkv, ob);
  gemm128<1, 6><<<(NTOK / 128) * (DMODEL / 128), 256, 0, stream>>>(
      ob, opw, NTOK, DMODEL, DMODEL, opb, x, x1, nullptr, nullptr, nullptr, nullptr);

  // 3. routing
  ln2_gate<<<NTOK, 256, 0, stream>>>(x1, ln2w, ln2b, gatew, h2, outlg, selw, seli);
  route_count<<<32, 256, 0, stream>>>(seli, bcnt);
  route_scan<<<1, 64, 0, stream>>>(bcnt, offs, bbas, wl, nwork);
  route_place<<<32, 256, 0, stream>>>(seli, bbas, perm, posm);

  // 4. expert FFNs on compacted work list (live 128-row tiles only)
  gemm128<2, 12><<<MAXWL * (FFDIM / 128), 256, 0, stream>>>(
      h2, w1t, NGATH, FFDIM, DMODEL, b1, nullptr, mid, perm, offs, wl, nwork);
  gemm128<3, 6><<<MAXWL * (DMODEL / 128), 256, 0, stream>>>(
      mid, w2t, NGATH, DMODEL, FFDIM, b2, nullptr, eout, nullptr, offs, wl, nwork);

  // 5. combine + residual
  moe_combine<<<NTOK, 192, 0, stream>>>(x1, eout, posm, selw, outx);
}